// Round 1
// baseline (4621.277 us; speedup 1.0000x reference)
//
#include <hip/hip_runtime.h>

// GCN 2-layer + mean-pool + linear head, f32.
// Round 1: correctness-first baseline.
//   - deg via atomics, dis = rsqrt(deg+1) in-place
//   - h = A @ W via LDS-tiled f32 vector GEMM (no fp32 MFMA on CDNA4)
//   - edge aggregation via float4 gather + 4x atomicAdd scatter
//   - self-loop + bias + relu fused, in-place on agg
//   - pooling exploits sorted batch: per-thread run-length sums, few atomics
//   - tiny final 128x64x2 GEMV in one block

#define NN 100000
#define NG 128

__global__ __launch_bounds__(256) void deg_kernel(const int* __restrict__ dst,
                                                  float* __restrict__ deg, int E) {
    int i = blockIdx.x * blockDim.x + threadIdx.x;
    int stride = gridDim.x * blockDim.x;
    for (; i < E; i += stride) atomicAdd(&deg[dst[i]], 1.0f);
}

__global__ __launch_bounds__(256) void dis_kernel(float* __restrict__ deg, int N) {
    int i = blockIdx.x * blockDim.x + threadIdx.x;
    if (i < N) deg[i] = rsqrtf(deg[i] + 1.0f);
}

// A [N][K] row-major, W [K][COLS] row-major, Out [N][COLS].
// 64 rows/block, K-tile 32, 256 threads. Each thread: RPT rows x 4 cols.
template <int COLS>
__global__ __launch_bounds__(256) void gemm_rm(const float* __restrict__ A,
                                               const float* __restrict__ W,
                                               float* __restrict__ Out, int N, int K) {
    constexpr int TM = 64, KT = 32;
    constexpr int CG = COLS / 4;          // col groups of 4
    constexpr int RPT = TM / (256 / CG);  // rows per thread (128->8, 64->4)
    __shared__ float As[TM][KT + 1];
    __shared__ float Ws[KT][COLS];

    const int t = threadIdx.x;
    const int r0 = blockIdx.x * TM;
    const int cg = t % CG;
    const int rg = t / CG;

    float acc[RPT][4];
#pragma unroll
    for (int i = 0; i < RPT; ++i)
        acc[i][0] = acc[i][1] = acc[i][2] = acc[i][3] = 0.f;

    for (int k0 = 0; k0 < K; k0 += KT) {
        // stage A tile: 64x32 = 2048 elems
#pragma unroll
        for (int i = t; i < TM * KT; i += 256) {
            int r = i >> 5, k = i & 31;
            int gr = r0 + r;
            As[r][k] = (gr < N) ? A[(size_t)gr * K + k0 + k] : 0.f;
        }
        // stage W tile: 32xCOLS
#pragma unroll
        for (int i = t; i < KT * COLS; i += 256) {
            int k = i / COLS, c = i % COLS;
            Ws[k][c] = W[(size_t)(k0 + k) * COLS + c];
        }
        __syncthreads();
#pragma unroll 8
        for (int k = 0; k < KT; ++k) {
            const float4 wv = *(const float4*)&Ws[k][cg * 4];
#pragma unroll
            for (int i = 0; i < RPT; ++i) {
                const float av = As[rg * RPT + i][k];
                acc[i][0] = fmaf(av, wv.x, acc[i][0]);
                acc[i][1] = fmaf(av, wv.y, acc[i][1]);
                acc[i][2] = fmaf(av, wv.z, acc[i][2]);
                acc[i][3] = fmaf(av, wv.w, acc[i][3]);
            }
        }
        __syncthreads();
    }
#pragma unroll
    for (int i = 0; i < RPT; ++i) {
        int gr = r0 + rg * RPT + i;
        if (gr < N) {
            float4 v = make_float4(acc[i][0], acc[i][1], acc[i][2], acc[i][3]);
            *(float4*)&Out[(size_t)gr * COLS + cg * 4] = v;
        }
    }
}

// msg scatter: Agg[dst] += H[src] * dis[src]*dis[dst]
template <int COLS>
__global__ __launch_bounds__(256) void scatter_kernel(const int* __restrict__ src,
                                                      const int* __restrict__ dst,
                                                      const float* __restrict__ dis,
                                                      const float* __restrict__ H,
                                                      float* __restrict__ Agg, int E) {
    constexpr int TPE = COLS / 4;  // threads per edge (float4 each)
    constexpr int SH = (TPE == 32) ? 5 : 4;
    const long long total = (long long)E * TPE;
    long long i = (long long)blockIdx.x * blockDim.x + threadIdx.x;
    const long long stride = (long long)gridDim.x * blockDim.x;
    for (; i < total; i += stride) {
        const int e = (int)(i >> SH);
        const int c4 = (int)(i & (TPE - 1));
        const int s = src[e], d = dst[e];
        const float nrm = dis[s] * dis[d];
        const float4 v = *(const float4*)(H + (size_t)s * COLS + c4 * 4);
        float* out = Agg + (size_t)d * COLS + c4 * 4;
        atomicAdd(out + 0, v.x * nrm);
        atomicAdd(out + 1, v.y * nrm);
        atomicAdd(out + 2, v.z * nrm);
        atomicAdd(out + 3, v.w * nrm);
    }
}

// Agg = relu(Agg + H * dis^2 + b), in place
template <int COLS>
__global__ __launch_bounds__(256) void sbr_kernel(float* __restrict__ Agg,
                                                  const float* __restrict__ H,
                                                  const float* __restrict__ dis,
                                                  const float* __restrict__ bias, int N) {
    constexpr int C4 = COLS / 4;
    const int total = N * C4;
    const int i = blockIdx.x * blockDim.x + threadIdx.x;
    if (i >= total) return;
    const int n = i / C4;
    const int c4 = i % C4;
    float s = dis[n];
    s *= s;
    float4 a = *(float4*)(Agg + (size_t)i * 4);
    const float4 h = *(const float4*)(H + (size_t)i * 4);
    const float4 b = *(const float4*)(bias + c4 * 4);
    a.x = fmaxf(fmaf(h.x, s, a.x) + b.x, 0.f);
    a.y = fmaxf(fmaf(h.y, s, a.y) + b.y, 0.f);
    a.z = fmaxf(fmaf(h.z, s, a.z) + b.z, 0.f);
    a.w = fmaxf(fmaf(h.w, s, a.w) + b.w, 0.f);
    *(float4*)(Agg + (size_t)i * 4) = a;
}

// mean-pool prep: pooled[g][c] += sum of H[n][c] over nodes of graph g; cnt[g] += count.
// batch is sorted -> per-thread run-length accumulate, flush on graph change.
__global__ __launch_bounds__(256) void pool_kernel(const float* __restrict__ H,
                                                   const int* __restrict__ batch,
                                                   float* __restrict__ pooled,
                                                   float* __restrict__ cnt, int N) {
    constexpr int CHUNK = 1024;
    const int n0 = blockIdx.x * CHUNK;
    const int c = threadIdx.x & 63;
    const int r = threadIdx.x >> 6;  // 0..3
    int curg = -1;
    float sum = 0.f, csum = 0.f;
    for (int i = r; i < CHUNK; i += 4) {
        const int n = n0 + i;
        if (n >= N) break;
        const int g = batch[n];
        if (g != curg) {
            if (curg >= 0) {
                atomicAdd(&pooled[curg * 64 + c], sum);
                if (c == 0) atomicAdd(&cnt[curg], csum);
            }
            curg = g;
            sum = 0.f;
            csum = 0.f;
        }
        sum += H[(size_t)n * 64 + c];
        csum += 1.f;
    }
    if (curg >= 0) {
        atomicAdd(&pooled[curg * 64 + c], sum);
        if (c == 0) atomicAdd(&cnt[curg], csum);
    }
}

__global__ __launch_bounds__(256) void final_kernel(const float* __restrict__ pooled,
                                                    const float* __restrict__ cnt,
                                                    const float* __restrict__ Wlin,
                                                    const float* __restrict__ blin,
                                                    float* __restrict__ out) {
    const int t = threadIdx.x;  // 256 = 128 graphs x 2 outputs
    const int g = t >> 1, o = t & 1;
    const float inv = 1.0f / fmaxf(cnt[g], 1.0f);
    float s = 0.f;
#pragma unroll
    for (int j = 0; j < 64; ++j) s = fmaf(pooled[g * 64 + j], Wlin[j * 2 + o], s);
    out[t] = s * inv + blin[o];
}

extern "C" void kernel_launch(void* const* d_in, const int* in_sizes, int n_in,
                              void* d_out, int out_size, void* d_ws, size_t ws_size,
                              hipStream_t stream) {
    const float* x    = (const float*)d_in[0];
    const int*   edge = (const int*)d_in[1];
    const int*   batch= (const int*)d_in[2];
    const float* W1   = (const float*)d_in[3];
    const float* b1   = (const float*)d_in[4];
    const float* W2   = (const float*)d_in[5];
    const float* b2   = (const float*)d_in[6];
    const float* Wlin = (const float*)d_in[7];
    const float* blin = (const float*)d_in[8];
    float* out = (float*)d_out;

    const int N = NN;
    const int E = in_sizes[1] / 2;
    const int* src = edge;
    const int* dst = edge + E;

    char* ws = (char*)d_ws;
    size_t off = 0;
    auto alloc = [&](size_t bytes) -> void* {
        void* p = ws + off;
        off += (bytes + 511) & ~(size_t)511;
        return p;
    };
    float* dis    = (float*)alloc((size_t)N * 4);           // deg then dis, in place
    float* h1     = (float*)alloc((size_t)N * 128 * 4);     // 51.2 MB
    float* agg1   = (float*)alloc((size_t)N * 128 * 4);     // 51.2 MB
    float* pooled = (float*)alloc((size_t)NG * 64 * 4);
    float* cnt    = (float*)alloc((size_t)NG * 4);
    // layer-2 buffers reuse h1's region (h1 dead after sbr1)
    float* h2   = h1;
    float* agg2 = (float*)((char*)h1 + (size_t)N * 64 * 4);

    // zero accumulators
    hipMemsetAsync(dis, 0, (size_t)N * 4, stream);
    hipMemsetAsync(agg1, 0, (size_t)N * 128 * 4, stream);
    hipMemsetAsync(pooled, 0, (size_t)NG * 64 * 4, stream);
    hipMemsetAsync(cnt, 0, (size_t)NG * 4, stream);

    // degree + normalization
    deg_kernel<<<2048, 256, 0, stream>>>(dst, dis, E);
    dis_kernel<<<(N + 255) / 256, 256, 0, stream>>>(dis, N);

    // layer 1
    gemm_rm<128><<<(N + 63) / 64, 256, 0, stream>>>(x, W1, h1, N, 384);
    scatter_kernel<128><<<8192, 256, 0, stream>>>(src, dst, dis, h1, agg1, E);
    sbr_kernel<128><<<(N * 32 + 255) / 256, 256, 0, stream>>>(agg1, h1, dis, b1, N);

    // layer 2 (h1 region now reused: h2 at base, agg2 after it)
    hipMemsetAsync(agg2, 0, (size_t)N * 64 * 4, stream);
    gemm_rm<64><<<(N + 63) / 64, 256, 0, stream>>>(agg1, W2, h2, N, 128);
    scatter_kernel<64><<<8192, 256, 0, stream>>>(src, dst, dis, h2, agg2, E);
    sbr_kernel<64><<<(N * 16 + 255) / 256, 256, 0, stream>>>(agg2, h2, dis, b2, N);

    // pool + head
    pool_kernel<<<(N + 1023) / 1024, 256, 0, stream>>>(agg2, batch, pooled, cnt, N);
    final_kernel<<<1, 256, 0, stream>>>(pooled, cnt, Wlin, blin, out);
}

// Round 2
// 994.937 us; speedup vs baseline: 4.6448x; 4.6448x over previous
//
#include <hip/hip_runtime.h>

// GCN 2-layer + mean-pool + linear head, f32.
// Round 2: replace atomic scatter with CSR gather aggregation.
//   - deg via atomics (int-valued float), dis = rsqrt(deg+1) in-place
//   - row_ptr via single-block 1024-thread scan (N=100k -> 98 elems/thread)
//   - csr_fill: counting-sort edges by dst (int atomics on fill counters)
//   - agg_csr: one wave per dst node, gather H[src] rows, fused
//     self-loop + bias + relu, single coalesced write. NO float atomics.
//   - GEMMs unchanged from round 1 (LDS-tiled f32 vector GEMM)

#define NN 100000
#define NG 128

__global__ __launch_bounds__(256) void deg_kernel(const int* __restrict__ dst,
                                                  float* __restrict__ deg, int E) {
    int i = blockIdx.x * blockDim.x + threadIdx.x;
    int stride = gridDim.x * blockDim.x;
    for (; i < E; i += stride) atomicAdd(&deg[dst[i]], 1.0f);
}

__global__ __launch_bounds__(256) void dis_kernel(float* __restrict__ deg, int N) {
    int i = blockIdx.x * blockDim.x + threadIdx.x;
    if (i < N) deg[i] = rsqrtf(deg[i] + 1.0f);
}

// Exclusive prefix sum of (int)deg -> rowptr[N+1]. Single block, 1024 threads.
__global__ __launch_bounds__(1024) void rowptr_kernel(const float* __restrict__ deg,
                                                      int* __restrict__ rowptr, int N) {
    __shared__ int part[1024];
    const int t = threadIdx.x;
    const int chunk = (N + 1023) / 1024;
    const int lo = t * chunk;
    const int hi = min(N, lo + chunk);
    int s = 0;
    for (int i = lo; i < hi; ++i) s += (int)deg[i];
    part[t] = s;
    __syncthreads();
    // inclusive Hillis-Steele scan
    for (int d = 1; d < 1024; d <<= 1) {
        int add = (t >= d) ? part[t - d] : 0;
        __syncthreads();
        part[t] += add;
        __syncthreads();
    }
    int run = part[t] - s;  // exclusive prefix for this chunk
    for (int i = lo; i < hi; ++i) {
        rowptr[i] = run;
        run += (int)deg[i];
    }
    if (t == 1023) rowptr[N] = run;  // == E
}

// counting-sort edges into CSR-by-dst: col[pos] = src
__global__ __launch_bounds__(256) void csr_fill(const int* __restrict__ src,
                                                const int* __restrict__ dst,
                                                const int* __restrict__ rowptr,
                                                int* __restrict__ fill,
                                                int* __restrict__ col, int E) {
    int i = blockIdx.x * blockDim.x + threadIdx.x;
    int stride = gridDim.x * blockDim.x;
    for (; i < E; i += stride) {
        const int d = dst[i];
        const int pos = rowptr[d] + atomicAdd(&fill[d], 1);
        col[pos] = src[i];
    }
}

// A [N][K] row-major, W [K][COLS] row-major, Out [N][COLS].
// 64 rows/block, K-tile 32, 256 threads. Each thread: RPT rows x 4 cols.
template <int COLS>
__global__ __launch_bounds__(256) void gemm_rm(const float* __restrict__ A,
                                               const float* __restrict__ W,
                                               float* __restrict__ Out, int N, int K) {
    constexpr int TM = 64, KT = 32;
    constexpr int CG = COLS / 4;          // col groups of 4
    constexpr int RPT = TM / (256 / CG);  // rows per thread (128->8, 64->4)
    __shared__ float As[TM][KT + 1];
    __shared__ float Ws[KT][COLS];

    const int t = threadIdx.x;
    const int r0 = blockIdx.x * TM;
    const int cg = t % CG;
    const int rg = t / CG;

    float acc[RPT][4];
#pragma unroll
    for (int i = 0; i < RPT; ++i)
        acc[i][0] = acc[i][1] = acc[i][2] = acc[i][3] = 0.f;

    for (int k0 = 0; k0 < K; k0 += KT) {
#pragma unroll
        for (int i = t; i < TM * KT; i += 256) {
            int r = i >> 5, k = i & 31;
            int gr = r0 + r;
            As[r][k] = (gr < N) ? A[(size_t)gr * K + k0 + k] : 0.f;
        }
#pragma unroll
        for (int i = t; i < KT * COLS; i += 256) {
            int k = i / COLS, c = i % COLS;
            Ws[k][c] = W[(size_t)(k0 + k) * COLS + c];
        }
        __syncthreads();
#pragma unroll 8
        for (int k = 0; k < KT; ++k) {
            const float4 wv = *(const float4*)&Ws[k][cg * 4];
#pragma unroll
            for (int i = 0; i < RPT; ++i) {
                const float av = As[rg * RPT + i][k];
                acc[i][0] = fmaf(av, wv.x, acc[i][0]);
                acc[i][1] = fmaf(av, wv.y, acc[i][1]);
                acc[i][2] = fmaf(av, wv.z, acc[i][2]);
                acc[i][3] = fmaf(av, wv.w, acc[i][3]);
            }
        }
        __syncthreads();
    }
#pragma unroll
    for (int i = 0; i < RPT; ++i) {
        int gr = r0 + rg * RPT + i;
        if (gr < N) {
            float4 v = make_float4(acc[i][0], acc[i][1], acc[i][2], acc[i][3]);
            *(float4*)&Out[(size_t)gr * COLS + cg * 4] = v;
        }
    }
}

// CSR gather aggregation, one wave per dst node.
// Out[d] = relu( dis[d] * sum_s(H[s]*dis[s]) + dis[d]^2 * H[d] + bias )
template <int COLS>
__global__ __launch_bounds__(256) void agg_csr(const int* __restrict__ rowptr,
                                               const int* __restrict__ col,
                                               const float* __restrict__ dis,
                                               const float* __restrict__ H,
                                               const float* __restrict__ bias,
                                               float* __restrict__ Out, int N) {
    constexpr int VPL = COLS / 64;  // floats per lane: 2 (COLS=128) or 1 (COLS=64)
    const int wid = (int)((blockIdx.x * blockDim.x + threadIdx.x) >> 6);
    const int lane = threadIdx.x & 63;
    if (wid >= N) return;
    const int node = wid;
    const int base = rowptr[node];
    const int len = rowptr[node + 1] - base;

    float acc[VPL];
#pragma unroll
    for (int v = 0; v < VPL; ++v) acc[v] = 0.f;

    for (int j0 = 0; j0 < len; j0 += 64) {
        const int remain = min(64, len - j0);
        const int sidx = (lane < remain) ? col[base + j0 + lane] : 0;
        for (int j = 0; j < remain; ++j) {
            const int s = __shfl(sidx, j);
            const float w = dis[s];
            const float* hp = H + (size_t)s * COLS + lane * VPL;
            if (VPL == 2) {
                const float2 hv = *(const float2*)hp;
                acc[0] = fmaf(hv.x, w, acc[0]);
                acc[1] = fmaf(hv.y, w, acc[1]);
            } else {
                acc[0] = fmaf(hp[0], w, acc[0]);
            }
        }
    }

    const float dd = dis[node];
    const float* hself = H + (size_t)node * COLS + lane * VPL;
    float* outp = Out + (size_t)node * COLS + lane * VPL;
#pragma unroll
    for (int v = 0; v < VPL; ++v) {
        const float r = fmaf(acc[v], dd, hself[v] * dd * dd) + bias[lane * VPL + v];
        outp[v] = fmaxf(r, 0.f);
    }
}

// mean-pool prep: batch sorted -> per-thread run-length accumulate.
__global__ __launch_bounds__(256) void pool_kernel(const float* __restrict__ H,
                                                   const int* __restrict__ batch,
                                                   float* __restrict__ pooled,
                                                   float* __restrict__ cnt, int N) {
    constexpr int CHUNK = 1024;
    const int n0 = blockIdx.x * CHUNK;
    const int c = threadIdx.x & 63;
    const int r = threadIdx.x >> 6;  // 0..3
    int curg = -1;
    float sum = 0.f, csum = 0.f;
    for (int i = r; i < CHUNK; i += 4) {
        const int n = n0 + i;
        if (n >= N) break;
        const int g = batch[n];
        if (g != curg) {
            if (curg >= 0) {
                atomicAdd(&pooled[curg * 64 + c], sum);
                if (c == 0) atomicAdd(&cnt[curg], csum);
            }
            curg = g;
            sum = 0.f;
            csum = 0.f;
        }
        sum += H[(size_t)n * 64 + c];
        csum += 1.f;
    }
    if (curg >= 0) {
        atomicAdd(&pooled[curg * 64 + c], sum);
        if (c == 0) atomicAdd(&cnt[curg], csum);
    }
}

__global__ __launch_bounds__(256) void final_kernel(const float* __restrict__ pooled,
                                                    const float* __restrict__ cnt,
                                                    const float* __restrict__ Wlin,
                                                    const float* __restrict__ blin,
                                                    float* __restrict__ out) {
    const int t = threadIdx.x;  // 256 = 128 graphs x 2 outputs
    const int g = t >> 1, o = t & 1;
    const float inv = 1.0f / fmaxf(cnt[g], 1.0f);
    float s = 0.f;
#pragma unroll
    for (int j = 0; j < 64; ++j) s = fmaf(pooled[g * 64 + j], Wlin[j * 2 + o], s);
    out[t] = s * inv + blin[o];
}

extern "C" void kernel_launch(void* const* d_in, const int* in_sizes, int n_in,
                              void* d_out, int out_size, void* d_ws, size_t ws_size,
                              hipStream_t stream) {
    const float* x     = (const float*)d_in[0];
    const int*   edge  = (const int*)d_in[1];
    const int*   batch = (const int*)d_in[2];
    const float* W1    = (const float*)d_in[3];
    const float* b1    = (const float*)d_in[4];
    const float* W2    = (const float*)d_in[5];
    const float* b2    = (const float*)d_in[6];
    const float* Wlin  = (const float*)d_in[7];
    const float* blin  = (const float*)d_in[8];
    float* out = (float*)d_out;

    const int N = NN;
    const int E = in_sizes[1] / 2;
    const int* src = edge;
    const int* dst = edge + E;

    char* ws = (char*)d_ws;
    size_t off = 0;
    auto alloc = [&](size_t bytes) -> void* {
        void* p = ws + off;
        off += (bytes + 511) & ~(size_t)511;
        return p;
    };
    float* dis    = (float*)alloc((size_t)N * 4);            // deg, then dis in-place
    int*   rowptr = (int*)alloc((size_t)(N + 1) * 4);
    int*   fill   = (int*)alloc((size_t)N * 4);
    int*   col    = (int*)alloc((size_t)E * 4);              // 6.4 MB
    float* h1     = (float*)alloc((size_t)N * 128 * 4);      // 51.2 MB
    float* agg1   = (float*)alloc((size_t)N * 128 * 4);      // 51.2 MB
    float* pooled = (float*)alloc((size_t)NG * 64 * 4);
    float* cnt    = (float*)alloc((size_t)NG * 4);
    // layer-2 buffers reuse h1's region (h1 dead after agg_csr<128>)
    float* h2   = h1;
    float* agg2 = (float*)((char*)h1 + (size_t)N * 64 * 4);

    hipMemsetAsync(dis, 0, (size_t)N * 4, stream);
    hipMemsetAsync(fill, 0, (size_t)N * 4, stream);
    hipMemsetAsync(pooled, 0, (size_t)NG * 64 * 4, stream);
    hipMemsetAsync(cnt, 0, (size_t)NG * 4, stream);

    // degree, CSR build, normalization
    deg_kernel<<<2048, 256, 0, stream>>>(dst, dis, E);
    rowptr_kernel<<<1, 1024, 0, stream>>>(dis, rowptr, N);
    csr_fill<<<2048, 256, 0, stream>>>(src, dst, rowptr, fill, col, E);
    dis_kernel<<<(N + 255) / 256, 256, 0, stream>>>(dis, N);

    // layer 1
    gemm_rm<128><<<(N + 63) / 64, 256, 0, stream>>>(x, W1, h1, N, 384);
    agg_csr<128><<<(N + 3) / 4, 256, 0, stream>>>(rowptr, col, dis, h1, b1, agg1, N);

    // layer 2
    gemm_rm<64><<<(N + 63) / 64, 256, 0, stream>>>(agg1, W2, h2, N, 128);
    agg_csr<64><<<(N + 3) / 4, 256, 0, stream>>>(rowptr, col, dis, h2, b2, agg2, N);

    // pool + head
    pool_kernel<<<(N + 1023) / 1024, 256, 0, stream>>>(agg2, batch, pooled, cnt, N);
    final_kernel<<<1, 256, 0, stream>>>(pooled, cnt, Wlin, blin, out);
}

// Round 3
// 835.971 us; speedup vs baseline: 5.5280x; 1.1902x over previous
//
#include <hip/hip_runtime.h>

// GCN 2-layer + mean-pool + linear head, f32.
// Round 3: GEMMs via MFMA with split-bf16 (hi+lo) emulation of f32.
//   x*w ~= xh*wh + xh*wl + xl*wh  (error ~2^-17 relative, f32 accumulate)
//   BM=128, BN=full width (128 / 64), BK=32, 4 waves, 16x16x32 bf16 MFMA.
//   LDS tiles padded to LDT=40 shorts/row (80 B) -> bank-balanced b128 reads.
// CSR gather aggregation unchanged from round 2.

#define NN 100000
#define NG 128

typedef __attribute__((ext_vector_type(8))) short short8;
typedef __attribute__((ext_vector_type(4))) float f32x4;

__device__ __forceinline__ unsigned short f2bf(float f) {
    union { float f; unsigned u; } v; v.f = f;
    unsigned r = v.u + 0x7fffu + ((v.u >> 16) & 1u);  // round-nearest-even
    return (unsigned short)(r >> 16);
}
__device__ __forceinline__ float bf2f(unsigned short h) {
    union { unsigned u; float f; } v; v.u = ((unsigned)h) << 16;
    return v.f;
}

__global__ __launch_bounds__(256) void deg_kernel(const int* __restrict__ dst,
                                                  float* __restrict__ deg, int E) {
    int i = blockIdx.x * blockDim.x + threadIdx.x;
    int stride = gridDim.x * blockDim.x;
    for (; i < E; i += stride) atomicAdd(&deg[dst[i]], 1.0f);
}

__global__ __launch_bounds__(256) void dis_kernel(float* __restrict__ deg, int N) {
    int i = blockIdx.x * blockDim.x + threadIdx.x;
    if (i < N) deg[i] = rsqrtf(deg[i] + 1.0f);
}

// Exclusive prefix sum of (int)deg -> rowptr[N+1]. Single block, 1024 threads.
__global__ __launch_bounds__(1024) void rowptr_kernel(const float* __restrict__ deg,
                                                      int* __restrict__ rowptr, int N) {
    __shared__ int part[1024];
    const int t = threadIdx.x;
    const int chunk = (N + 1023) / 1024;
    const int lo = t * chunk;
    const int hi = min(N, lo + chunk);
    int s = 0;
    for (int i = lo; i < hi; ++i) s += (int)deg[i];
    part[t] = s;
    __syncthreads();
    for (int d = 1; d < 1024; d <<= 1) {
        int add = (t >= d) ? part[t - d] : 0;
        __syncthreads();
        part[t] += add;
        __syncthreads();
    }
    int run = part[t] - s;
    for (int i = lo; i < hi; ++i) {
        rowptr[i] = run;
        run += (int)deg[i];
    }
    if (t == 1023) rowptr[N] = run;
}

__global__ __launch_bounds__(256) void csr_fill(const int* __restrict__ src,
                                                const int* __restrict__ dst,
                                                const int* __restrict__ rowptr,
                                                int* __restrict__ fill,
                                                int* __restrict__ col, int E) {
    int i = blockIdx.x * blockDim.x + threadIdx.x;
    int stride = gridDim.x * blockDim.x;
    for (; i < E; i += stride) {
        const int d = dst[i];
        const int pos = rowptr[d] + atomicAdd(&fill[d], 1);
        col[pos] = src[i];
    }
}

// MFMA split-bf16 GEMM: A [N][K] f32 row-major, W [K][BN] f32 row-major,
// Out [N][BN]. One block = 128 rows x full BN width. K % 32 == 0.
template <int BN>
__global__ __launch_bounds__(256) void gemm_mfma(const float* __restrict__ A,
                                                 const float* __restrict__ W,
                                                 float* __restrict__ Out,
                                                 int N, int K) {
    constexpr int BM = 128, BK = 32, LDT = 40;  // 40 shorts = 80 B row pitch
    constexpr int WROWS = (BN == 128) ? 2 : 4;
    constexpr int WCOLS = (BN == 128) ? 2 : 1;
    constexpr int WTM = BM / WROWS;  // 64 or 32
    constexpr int WTN = BN / WCOLS;  // 64
    constexpr int MF = WTM / 16;     // 4 or 2
    constexpr int NF = WTN / 16;     // 4

    __shared__ unsigned short AsH[BM * LDT];
    __shared__ unsigned short AsL[BM * LDT];
    __shared__ unsigned short BtH[BN * LDT];
    __shared__ unsigned short BtL[BN * LDT];

    const int t = threadIdx.x;
    const int wid = t >> 6, lane = t & 63;
    const int wr = wid / WCOLS, wc = wid % WCOLS;
    const int lr = lane & 15;           // m (A) / n (B) within fragment
    const int lk = (lane >> 4) * 8;     // k offset within fragment
    const int r0 = blockIdx.x * BM;

    f32x4 acc[MF][NF];
#pragma unroll
    for (int m = 0; m < MF; ++m)
#pragma unroll
        for (int n = 0; n < NF; ++n) acc[m][n] = (f32x4){0.f, 0.f, 0.f, 0.f};

    // A staging geometry: 128x32 f32 = 1024 float4, 4 iters
    const int s_row = t >> 3;          // 0..31
    const int s_c4 = (t & 7) * 4;      // 0,4,..,28
    // B staging geometry
    constexpr int TPR = BN / 4;        // threads per k-row (32 or 16)
    constexpr int KSTR = 256 / TPR;    // 8 or 16
    const int s_bk = t / TPR;
    const int s_bn4 = (t % TPR) * 4;

    for (int k0 = 0; k0 < K; k0 += BK) {
        // ---- stage A tile (f32 -> bf16 hi/lo) ----
#pragma unroll
        for (int it = 0; it < 4; ++it) {
            const int rr = s_row + it * 32;
            const int gr = r0 + rr;
            float4 v = make_float4(0.f, 0.f, 0.f, 0.f);
            if (gr < N) v = *(const float4*)&A[(size_t)gr * K + k0 + s_c4];
            ushort4 h, l;
            h.x = f2bf(v.x); l.x = f2bf(v.x - bf2f(h.x));
            h.y = f2bf(v.y); l.y = f2bf(v.y - bf2f(h.y));
            h.z = f2bf(v.z); l.z = f2bf(v.z - bf2f(h.z));
            h.w = f2bf(v.w); l.w = f2bf(v.w - bf2f(h.w));
            *(ushort4*)&AsH[rr * LDT + s_c4] = h;
            *(ushort4*)&AsL[rr * LDT + s_c4] = l;
        }
        // ---- stage B tile transposed (Bt[n][k]) ----
#pragma unroll
        for (int it = 0; it < BK / KSTR; ++it) {
            const int kk = s_bk + it * KSTR;
            const float4 v = *(const float4*)&W[(size_t)(k0 + kk) * BN + s_bn4];
            const float vv[4] = {v.x, v.y, v.z, v.w};
#pragma unroll
            for (int j = 0; j < 4; ++j) {
                const unsigned short h = f2bf(vv[j]);
                const unsigned short l = f2bf(vv[j] - bf2f(h));
                BtH[(s_bn4 + j) * LDT + kk] = h;
                BtL[(s_bn4 + j) * LDT + kk] = l;
            }
        }
        __syncthreads();

        // ---- fragments + MFMA ----
        short8 bH[NF], bL[NF];
#pragma unroll
        for (int n = 0; n < NF; ++n) {
            const int cn = wc * WTN + n * 16 + lr;
            bH[n] = *(const short8*)&BtH[cn * LDT + lk];
            bL[n] = *(const short8*)&BtL[cn * LDT + lk];
        }
#pragma unroll
        for (int m = 0; m < MF; ++m) {
            const int row = wr * WTM + m * 16 + lr;
            const short8 aH = *(const short8*)&AsH[row * LDT + lk];
            const short8 aL = *(const short8*)&AsL[row * LDT + lk];
#pragma unroll
            for (int n = 0; n < NF; ++n) {
                acc[m][n] = __builtin_amdgcn_mfma_f32_16x16x32_bf16(aH, bH[n], acc[m][n], 0, 0, 0);
                acc[m][n] = __builtin_amdgcn_mfma_f32_16x16x32_bf16(aH, bL[n], acc[m][n], 0, 0, 0);
                acc[m][n] = __builtin_amdgcn_mfma_f32_16x16x32_bf16(aL, bH[n], acc[m][n], 0, 0, 0);
            }
        }
        __syncthreads();
    }

    // ---- C write: D[(lane>>4)*4 + r][lane&15] per fragment ----
#pragma unroll
    for (int m = 0; m < MF; ++m) {
#pragma unroll
        for (int n = 0; n < NF; ++n) {
            const int row0 = r0 + wr * WTM + m * 16 + (lane >> 4) * 4;
            const int cn = wc * WTN + n * 16 + lr;
#pragma unroll
            for (int r = 0; r < 4; ++r) {
                if (row0 + r < N) Out[(size_t)(row0 + r) * BN + cn] = acc[m][n][r];
            }
        }
    }
}

// CSR gather aggregation, one wave per dst node.
// Out[d] = relu( dis[d] * sum_s(H[s]*dis[s]) + dis[d]^2 * H[d] + bias )
template <int COLS>
__global__ __launch_bounds__(256) void agg_csr(const int* __restrict__ rowptr,
                                               const int* __restrict__ col,
                                               const float* __restrict__ dis,
                                               const float* __restrict__ H,
                                               const float* __restrict__ bias,
                                               float* __restrict__ Out, int N) {
    constexpr int VPL = COLS / 64;  // floats per lane
    const int wid = (int)((blockIdx.x * blockDim.x + threadIdx.x) >> 6);
    const int lane = threadIdx.x & 63;
    if (wid >= N) return;
    const int node = wid;
    const int base = rowptr[node];
    const int len = rowptr[node + 1] - base;

    float acc[VPL];
#pragma unroll
    for (int v = 0; v < VPL; ++v) acc[v] = 0.f;

    for (int j0 = 0; j0 < len; j0 += 64) {
        const int remain = min(64, len - j0);
        const int sidx = (lane < remain) ? col[base + j0 + lane] : 0;
        for (int j = 0; j < remain; ++j) {
            const int s = __shfl(sidx, j);
            const float w = dis[s];
            const float* hp = H + (size_t)s * COLS + lane * VPL;
            if (VPL == 2) {
                const float2 hv = *(const float2*)hp;
                acc[0] = fmaf(hv.x, w, acc[0]);
                acc[1] = fmaf(hv.y, w, acc[1]);
            } else {
                acc[0] = fmaf(hp[0], w, acc[0]);
            }
        }
    }

    const float dd = dis[node];
    const float* hself = H + (size_t)node * COLS + lane * VPL;
    float* outp = Out + (size_t)node * COLS + lane * VPL;
#pragma unroll
    for (int v = 0; v < VPL; ++v) {
        const float r = fmaf(acc[v], dd, hself[v] * dd * dd) + bias[lane * VPL + v];
        outp[v] = fmaxf(r, 0.f);
    }
}

__global__ __launch_bounds__(256) void pool_kernel(const float* __restrict__ H,
                                                   const int* __restrict__ batch,
                                                   float* __restrict__ pooled,
                                                   float* __restrict__ cnt, int N) {
    constexpr int CHUNK = 1024;
    const int n0 = blockIdx.x * CHUNK;
    const int c = threadIdx.x & 63;
    const int r = threadIdx.x >> 6;
    int curg = -1;
    float sum = 0.f, csum = 0.f;
    for (int i = r; i < CHUNK; i += 4) {
        const int n = n0 + i;
        if (n >= N) break;
        const int g = batch[n];
        if (g != curg) {
            if (curg >= 0) {
                atomicAdd(&pooled[curg * 64 + c], sum);
                if (c == 0) atomicAdd(&cnt[curg], csum);
            }
            curg = g;
            sum = 0.f;
            csum = 0.f;
        }
        sum += H[(size_t)n * 64 + c];
        csum += 1.f;
    }
    if (curg >= 0) {
        atomicAdd(&pooled[curg * 64 + c], sum);
        if (c == 0) atomicAdd(&cnt[curg], csum);
    }
}

__global__ __launch_bounds__(256) void final_kernel(const float* __restrict__ pooled,
                                                    const float* __restrict__ cnt,
                                                    const float* __restrict__ Wlin,
                                                    const float* __restrict__ blin,
                                                    float* __restrict__ out) {
    const int t = threadIdx.x;
    const int g = t >> 1, o = t & 1;
    const float inv = 1.0f / fmaxf(cnt[g], 1.0f);
    float s = 0.f;
#pragma unroll
    for (int j = 0; j < 64; ++j) s = fmaf(pooled[g * 64 + j], Wlin[j * 2 + o], s);
    out[t] = s * inv + blin[o];
}

extern "C" void kernel_launch(void* const* d_in, const int* in_sizes, int n_in,
                              void* d_out, int out_size, void* d_ws, size_t ws_size,
                              hipStream_t stream) {
    const float* x     = (const float*)d_in[0];
    const int*   edge  = (const int*)d_in[1];
    const int*   batch = (const int*)d_in[2];
    const float* W1    = (const float*)d_in[3];
    const float* b1    = (const float*)d_in[4];
    const float* W2    = (const float*)d_in[5];
    const float* b2    = (const float*)d_in[6];
    const float* Wlin  = (const float*)d_in[7];
    const float* blin  = (const float*)d_in[8];
    float* out = (float*)d_out;

    const int N = NN;
    const int E = in_sizes[1] / 2;
    const int* src = edge;
    const int* dst = edge + E;

    char* ws = (char*)d_ws;
    size_t off = 0;
    auto alloc = [&](size_t bytes) -> void* {
        void* p = ws + off;
        off += (bytes + 511) & ~(size_t)511;
        return p;
    };
    float* dis    = (float*)alloc((size_t)N * 4);
    int*   rowptr = (int*)alloc((size_t)(N + 1) * 4);
    int*   fill   = (int*)alloc((size_t)N * 4);
    int*   col    = (int*)alloc((size_t)E * 4);
    float* h1     = (float*)alloc((size_t)N * 128 * 4);
    float* agg1   = (float*)alloc((size_t)N * 128 * 4);
    float* pooled = (float*)alloc((size_t)NG * 64 * 4);
    float* cnt    = (float*)alloc((size_t)NG * 4);
    float* h2   = h1;
    float* agg2 = (float*)((char*)h1 + (size_t)N * 64 * 4);

    hipMemsetAsync(dis, 0, (size_t)N * 4, stream);
    hipMemsetAsync(fill, 0, (size_t)N * 4, stream);
    hipMemsetAsync(pooled, 0, (size_t)NG * 64 * 4, stream);
    hipMemsetAsync(cnt, 0, (size_t)NG * 4, stream);

    deg_kernel<<<2048, 256, 0, stream>>>(dst, dis, E);
    rowptr_kernel<<<1, 1024, 0, stream>>>(dis, rowptr, N);
    csr_fill<<<2048, 256, 0, stream>>>(src, dst, rowptr, fill, col, E);
    dis_kernel<<<(N + 255) / 256, 256, 0, stream>>>(dis, N);

    const int gblocks = (N + 127) / 128;
    // layer 1
    gemm_mfma<128><<<gblocks, 256, 0, stream>>>(x, W1, h1, N, 384);
    agg_csr<128><<<(N + 3) / 4, 256, 0, stream>>>(rowptr, col, dis, h1, b1, agg1, N);

    // layer 2
    gemm_mfma<64><<<gblocks, 256, 0, stream>>>(agg1, W2, h2, N, 128);
    agg_csr<64><<<(N + 3) / 4, 256, 0, stream>>>(rowptr, col, dis, h2, b2, agg2, N);

    // pool + head
    pool_kernel<<<(N + 1023) / 1024, 256, 0, stream>>>(agg2, batch, pooled, cnt, N);
    final_kernel<<<1, 256, 0, stream>>>(pooled, cnt, Wlin, blin, out);
}

// Round 4
// 713.014 us; speedup vs baseline: 6.4813x; 1.1724x over previous
//
#include <hip/hip_runtime.h>

// GCN 2-layer + mean-pool + linear head, f32.
// Round 4: fix the 161us single-block rowptr scan -> 3-kernel device scan.
//   - deg via int atomics
//   - scan_part: 98 blocks x 1024 elems, int4 loads, shfl-xor wave reduce
//   - scan_top: one block scans the 98 block sums (exclusive)
//   - scan_write: intra-block LDS scan + running prefix -> rowptr; fused
//     dis = rsqrt(deg+1) (removes dis_kernel)
// GEMMs: MFMA split-bf16 (hi+lo), unchanged from round 3.
// Aggregation: CSR gather, one wave per dst node, unchanged from round 2.

#define NN 100000
#define NG 128
#define SCHUNK 1024

typedef __attribute__((ext_vector_type(8))) short short8;
typedef __attribute__((ext_vector_type(4))) float f32x4;

__device__ __forceinline__ unsigned short f2bf(float f) {
    union { float f; unsigned u; } v; v.f = f;
    unsigned r = v.u + 0x7fffu + ((v.u >> 16) & 1u);  // round-nearest-even
    return (unsigned short)(r >> 16);
}
__device__ __forceinline__ float bf2f(unsigned short h) {
    union { unsigned u; float f; } v; v.u = ((unsigned)h) << 16;
    return v.f;
}

__global__ __launch_bounds__(256) void deg_kernel(const int* __restrict__ dst,
                                                  int* __restrict__ deg, int E) {
    int i = blockIdx.x * blockDim.x + threadIdx.x;
    int stride = gridDim.x * blockDim.x;
    for (; i < E; i += stride) atomicAdd(&deg[dst[i]], 1);
}

// ---- 3-kernel exclusive scan of deg -> rowptr, fused dis = rsqrt(deg+1) ----
__global__ __launch_bounds__(256) void scan_part(const int* __restrict__ deg,
                                                 int* __restrict__ bsum, int N) {
    const int t = threadIdx.x;
    const int i = blockIdx.x * SCHUNK + t * 4;
    int4 v = make_int4(0, 0, 0, 0);
    if (i + 3 < N) v = *(const int4*)(deg + i);
    else {
        if (i < N) v.x = deg[i];
        if (i + 1 < N) v.y = deg[i + 1];
        if (i + 2 < N) v.z = deg[i + 2];
    }
    int s = v.x + v.y + v.z + v.w;
#pragma unroll
    for (int d = 1; d < 64; d <<= 1) s += __shfl_xor(s, d);
    __shared__ int ws[4];
    if ((t & 63) == 0) ws[t >> 6] = s;
    __syncthreads();
    if (t == 0) bsum[blockIdx.x] = ws[0] + ws[1] + ws[2] + ws[3];
}

__global__ __launch_bounds__(128) void scan_top(int* __restrict__ bsum, int NB) {
    __shared__ int sm[128];
    const int t = threadIdx.x;
    const int v = (t < NB) ? bsum[t] : 0;
    sm[t] = v;
    __syncthreads();
    for (int d = 1; d < 128; d <<= 1) {
        int a = (t >= d) ? sm[t - d] : 0;
        __syncthreads();
        sm[t] += a;
        __syncthreads();
    }
    if (t < NB) bsum[t] = sm[t] - v;  // exclusive
}

__global__ __launch_bounds__(256) void scan_write(const int* __restrict__ deg,
                                                  const int* __restrict__ bsum,
                                                  int* __restrict__ rowptr,
                                                  float* __restrict__ dis,
                                                  int N, int NB) {
    const int t = threadIdx.x;
    const int i = blockIdx.x * SCHUNK + t * 4;
    int4 v = make_int4(0, 0, 0, 0);
    if (i + 3 < N) v = *(const int4*)(deg + i);
    else {
        if (i < N) v.x = deg[i];
        if (i + 1 < N) v.y = deg[i + 1];
        if (i + 2 < N) v.z = deg[i + 2];
    }
    const int s = v.x + v.y + v.z + v.w;
    __shared__ int sm[256];
    sm[t] = s;
    __syncthreads();
    for (int d = 1; d < 256; d <<= 1) {
        int a = (t >= d) ? sm[t - d] : 0;
        __syncthreads();
        sm[t] += a;
        __syncthreads();
    }
    int run = bsum[blockIdx.x] + sm[t] - s;
    const int dv[4] = {v.x, v.y, v.z, v.w};
#pragma unroll
    for (int j = 0; j < 4; ++j) {
        if (i + j < N) {
            rowptr[i + j] = run;
            dis[i + j] = rsqrtf((float)dv[j] + 1.0f);
        }
        run += dv[j];
    }
    if (blockIdx.x == NB - 1 && t == 255) rowptr[N] = run;  // == E
}

__global__ __launch_bounds__(256) void csr_fill(const int* __restrict__ src,
                                                const int* __restrict__ dst,
                                                const int* __restrict__ rowptr,
                                                int* __restrict__ fill,
                                                int* __restrict__ col, int E) {
    int i = blockIdx.x * blockDim.x + threadIdx.x;
    int stride = gridDim.x * blockDim.x;
    for (; i < E; i += stride) {
        const int d = dst[i];
        const int pos = rowptr[d] + atomicAdd(&fill[d], 1);
        col[pos] = src[i];
    }
}

// MFMA split-bf16 GEMM: A [N][K] f32 row-major, W [K][BN] f32 row-major,
// Out [N][BN]. One block = 128 rows x full BN width. K % 32 == 0.
template <int BN>
__global__ __launch_bounds__(256) void gemm_mfma(const float* __restrict__ A,
                                                 const float* __restrict__ W,
                                                 float* __restrict__ Out,
                                                 int N, int K) {
    constexpr int BM = 128, BK = 32, LDT = 40;  // 40 shorts = 80 B row pitch
    constexpr int WROWS = (BN == 128) ? 2 : 4;
    constexpr int WCOLS = (BN == 128) ? 2 : 1;
    constexpr int WTM = BM / WROWS;
    constexpr int WTN = BN / WCOLS;
    constexpr int MF = WTM / 16;
    constexpr int NF = WTN / 16;

    __shared__ unsigned short AsH[BM * LDT];
    __shared__ unsigned short AsL[BM * LDT];
    __shared__ unsigned short BtH[BN * LDT];
    __shared__ unsigned short BtL[BN * LDT];

    const int t = threadIdx.x;
    const int wid = t >> 6, lane = t & 63;
    const int wr = wid / WCOLS, wc = wid % WCOLS;
    const int lr = lane & 15;
    const int lk = (lane >> 4) * 8;
    const int r0 = blockIdx.x * BM;

    f32x4 acc[MF][NF];
#pragma unroll
    for (int m = 0; m < MF; ++m)
#pragma unroll
        for (int n = 0; n < NF; ++n) acc[m][n] = (f32x4){0.f, 0.f, 0.f, 0.f};

    const int s_row = t >> 3;
    const int s_c4 = (t & 7) * 4;
    constexpr int TPR = BN / 4;
    constexpr int KSTR = 256 / TPR;
    const int s_bk = t / TPR;
    const int s_bn4 = (t % TPR) * 4;

    for (int k0 = 0; k0 < K; k0 += BK) {
#pragma unroll
        for (int it = 0; it < 4; ++it) {
            const int rr = s_row + it * 32;
            const int gr = r0 + rr;
            float4 v = make_float4(0.f, 0.f, 0.f, 0.f);
            if (gr < N) v = *(const float4*)&A[(size_t)gr * K + k0 + s_c4];
            ushort4 h, l;
            h.x = f2bf(v.x); l.x = f2bf(v.x - bf2f(h.x));
            h.y = f2bf(v.y); l.y = f2bf(v.y - bf2f(h.y));
            h.z = f2bf(v.z); l.z = f2bf(v.z - bf2f(h.z));
            h.w = f2bf(v.w); l.w = f2bf(v.w - bf2f(h.w));
            *(ushort4*)&AsH[rr * LDT + s_c4] = h;
            *(ushort4*)&AsL[rr * LDT + s_c4] = l;
        }
#pragma unroll
        for (int it = 0; it < BK / KSTR; ++it) {
            const int kk = s_bk + it * KSTR;
            const float4 v = *(const float4*)&W[(size_t)(k0 + kk) * BN + s_bn4];
            const float vv[4] = {v.x, v.y, v.z, v.w};
#pragma unroll
            for (int j = 0; j < 4; ++j) {
                const unsigned short h = f2bf(vv[j]);
                const unsigned short l = f2bf(vv[j] - bf2f(h));
                BtH[(s_bn4 + j) * LDT + kk] = h;
                BtL[(s_bn4 + j) * LDT + kk] = l;
            }
        }
        __syncthreads();

        short8 bH[NF], bL[NF];
#pragma unroll
        for (int n = 0; n < NF; ++n) {
            const int cn = wc * WTN + n * 16 + lr;
            bH[n] = *(const short8*)&BtH[cn * LDT + lk];
            bL[n] = *(const short8*)&BtL[cn * LDT + lk];
        }
#pragma unroll
        for (int m = 0; m < MF; ++m) {
            const int row = wr * WTM + m * 16 + lr;
            const short8 aH = *(const short8*)&AsH[row * LDT + lk];
            const short8 aL = *(const short8*)&AsL[row * LDT + lk];
#pragma unroll
            for (int n = 0; n < NF; ++n) {
                acc[m][n] = __builtin_amdgcn_mfma_f32_16x16x32_bf16(aH, bH[n], acc[m][n], 0, 0, 0);
                acc[m][n] = __builtin_amdgcn_mfma_f32_16x16x32_bf16(aH, bL[n], acc[m][n], 0, 0, 0);
                acc[m][n] = __builtin_amdgcn_mfma_f32_16x16x32_bf16(aL, bH[n], acc[m][n], 0, 0, 0);
            }
        }
        __syncthreads();
    }

#pragma unroll
    for (int m = 0; m < MF; ++m) {
#pragma unroll
        for (int n = 0; n < NF; ++n) {
            const int row0 = r0 + wr * WTM + m * 16 + (lane >> 4) * 4;
            const int cn = wc * WTN + n * 16 + lr;
#pragma unroll
            for (int r = 0; r < 4; ++r) {
                if (row0 + r < N) Out[(size_t)(row0 + r) * BN + cn] = acc[m][n][r];
            }
        }
    }
}

// CSR gather aggregation, one wave per dst node.
template <int COLS>
__global__ __launch_bounds__(256) void agg_csr(const int* __restrict__ rowptr,
                                               const int* __restrict__ col,
                                               const float* __restrict__ dis,
                                               const float* __restrict__ H,
                                               const float* __restrict__ bias,
                                               float* __restrict__ Out, int N) {
    constexpr int VPL = COLS / 64;
    const int wid = (int)((blockIdx.x * blockDim.x + threadIdx.x) >> 6);
    const int lane = threadIdx.x & 63;
    if (wid >= N) return;
    const int node = wid;
    const int base = rowptr[node];
    const int len = rowptr[node + 1] - base;

    float acc[VPL];
#pragma unroll
    for (int v = 0; v < VPL; ++v) acc[v] = 0.f;

    for (int j0 = 0; j0 < len; j0 += 64) {
        const int remain = min(64, len - j0);
        const int sidx = (lane < remain) ? col[base + j0 + lane] : 0;
        const float sw = (lane < remain) ? dis[sidx] : 0.f;
        for (int j = 0; j < remain; ++j) {
            const int s = __shfl(sidx, j);
            const float w = __shfl(sw, j);
            const float* hp = H + (size_t)s * COLS + lane * VPL;
            if (VPL == 2) {
                const float2 hv = *(const float2*)hp;
                acc[0] = fmaf(hv.x, w, acc[0]);
                acc[1] = fmaf(hv.y, w, acc[1]);
            } else {
                acc[0] = fmaf(hp[0], w, acc[0]);
            }
        }
    }

    const float dd = dis[node];
    const float* hself = H + (size_t)node * COLS + lane * VPL;
    float* outp = Out + (size_t)node * COLS + lane * VPL;
#pragma unroll
    for (int v = 0; v < VPL; ++v) {
        const float r = fmaf(acc[v], dd, hself[v] * dd * dd) + bias[lane * VPL + v];
        outp[v] = fmaxf(r, 0.f);
    }
}

__global__ __launch_bounds__(256) void pool_kernel(const float* __restrict__ H,
                                                   const int* __restrict__ batch,
                                                   float* __restrict__ pooled,
                                                   float* __restrict__ cnt, int N) {
    constexpr int CHUNK = 1024;
    const int n0 = blockIdx.x * CHUNK;
    const int c = threadIdx.x & 63;
    const int r = threadIdx.x >> 6;
    int curg = -1;
    float sum = 0.f, csum = 0.f;
    for (int i = r; i < CHUNK; i += 4) {
        const int n = n0 + i;
        if (n >= N) break;
        const int g = batch[n];
        if (g != curg) {
            if (curg >= 0) {
                atomicAdd(&pooled[curg * 64 + c], sum);
                if (c == 0) atomicAdd(&cnt[curg], csum);
            }
            curg = g;
            sum = 0.f;
            csum = 0.f;
        }
        sum += H[(size_t)n * 64 + c];
        csum += 1.f;
    }
    if (curg >= 0) {
        atomicAdd(&pooled[curg * 64 + c], sum);
        if (c == 0) atomicAdd(&cnt[curg], csum);
    }
}

__global__ __launch_bounds__(256) void final_kernel(const float* __restrict__ pooled,
                                                    const float* __restrict__ cnt,
                                                    const float* __restrict__ Wlin,
                                                    const float* __restrict__ blin,
                                                    float* __restrict__ out) {
    const int t = threadIdx.x;
    const int g = t >> 1, o = t & 1;
    const float inv = 1.0f / fmaxf(cnt[g], 1.0f);
    float s = 0.f;
#pragma unroll
    for (int j = 0; j < 64; ++j) s = fmaf(pooled[g * 64 + j], Wlin[j * 2 + o], s);
    out[t] = s * inv + blin[o];
}

extern "C" void kernel_launch(void* const* d_in, const int* in_sizes, int n_in,
                              void* d_out, int out_size, void* d_ws, size_t ws_size,
                              hipStream_t stream) {
    const float* x     = (const float*)d_in[0];
    const int*   edge  = (const int*)d_in[1];
    const int*   batch = (const int*)d_in[2];
    const float* W1    = (const float*)d_in[3];
    const float* b1    = (const float*)d_in[4];
    const float* W2    = (const float*)d_in[5];
    const float* b2    = (const float*)d_in[6];
    const float* Wlin  = (const float*)d_in[7];
    const float* blin  = (const float*)d_in[8];
    float* out = (float*)d_out;

    const int N = NN;
    const int E = in_sizes[1] / 2;
    const int* src = edge;
    const int* dst = edge + E;
    const int NB = (N + SCHUNK - 1) / SCHUNK;  // 98

    char* ws = (char*)d_ws;
    size_t off = 0;
    auto alloc = [&](size_t bytes) -> void* {
        void* p = ws + off;
        off += (bytes + 511) & ~(size_t)511;
        return p;
    };
    int*   deg    = (int*)alloc((size_t)N * 4);
    float* dis    = (float*)alloc((size_t)N * 4);
    int*   rowptr = (int*)alloc((size_t)(N + 1) * 4);
    int*   fill   = (int*)alloc((size_t)N * 4);
    int*   bsum   = (int*)alloc((size_t)NB * 4);
    int*   col    = (int*)alloc((size_t)E * 4);
    float* h1     = (float*)alloc((size_t)N * 128 * 4);
    float* agg1   = (float*)alloc((size_t)N * 128 * 4);
    float* pooled = (float*)alloc((size_t)NG * 64 * 4);
    float* cnt    = (float*)alloc((size_t)NG * 4);
    float* h2   = h1;
    float* agg2 = (float*)((char*)h1 + (size_t)N * 64 * 4);

    hipMemsetAsync(deg, 0, (size_t)N * 4, stream);
    hipMemsetAsync(fill, 0, (size_t)N * 4, stream);
    hipMemsetAsync(pooled, 0, (size_t)NG * 64 * 4, stream);
    hipMemsetAsync(cnt, 0, (size_t)NG * 4, stream);

    // degree + CSR build + normalization
    deg_kernel<<<2048, 256, 0, stream>>>(dst, deg, E);
    scan_part<<<NB, 256, 0, stream>>>(deg, bsum, N);
    scan_top<<<1, 128, 0, stream>>>(bsum, NB);
    scan_write<<<NB, 256, 0, stream>>>(deg, bsum, rowptr, dis, N, NB);
    csr_fill<<<2048, 256, 0, stream>>>(src, dst, rowptr, fill, col, E);

    const int gblocks = (N + 127) / 128;
    // layer 1
    gemm_mfma<128><<<gblocks, 256, 0, stream>>>(x, W1, h1, N, 384);
    agg_csr<128><<<(N + 3) / 4, 256, 0, stream>>>(rowptr, col, dis, h1, b1, agg1, N);

    // layer 2
    gemm_mfma<64><<<gblocks, 256, 0, stream>>>(agg1, W2, h2, N, 128);
    agg_csr<64><<<(N + 3) / 4, 256, 0, stream>>>(rowptr, col, dis, h2, b2, agg2, N);

    // pool + head
    pool_kernel<<<(N + 1023) / 1024, 256, 0, stream>>>(agg2, batch, pooled, cnt, N);
    final_kernel<<<1, 256, 0, stream>>>(pooled, cnt, Wlin, blin, out);
}

// Round 5
// 615.965 us; speedup vs baseline: 7.5025x; 1.1576x over previous
//
#include <hip/hip_runtime.h>

// GCN 2-layer + mean-pool + linear head, f32.
// Round 5: kill GEMM LDS bank conflicts (was 3.96e7/dispatch).
//   - pack_w: one-time W -> bf16 hi/lo in MFMA fragment order (global).
//     GEMM loads B fragments straight from global (L2-resident, lane*16,
//     coalesced) -> B never touches LDS, no B conversion in hot loop.
//   - A staged in fragment-packed LDS: per-wave write perm is a bijection
//     onto lane_f*16 (linear 1KB block) -> conflict-free writes AND reads.
//   - LDS 40KB -> 16KB, occupancy up.
// CSR gather aggregation + scan + pool unchanged from round 4.

#define NN 100000
#define NG 128
#define SCHUNK 1024

typedef __attribute__((ext_vector_type(8))) short short8;
typedef __attribute__((ext_vector_type(4))) float f32x4;

__device__ __forceinline__ unsigned short f2bf(float f) {
    union { float f; unsigned u; } v; v.f = f;
    unsigned r = v.u + 0x7fffu + ((v.u >> 16) & 1u);  // round-nearest-even
    return (unsigned short)(r >> 16);
}
__device__ __forceinline__ float bf2f(unsigned short h) {
    union { unsigned u; float f; } v; v.u = ((unsigned)h) << 16;
    return v.f;
}

__global__ __launch_bounds__(256) void deg_kernel(const int* __restrict__ dst,
                                                  int* __restrict__ deg, int E) {
    int i = blockIdx.x * blockDim.x + threadIdx.x;
    int stride = gridDim.x * blockDim.x;
    for (; i < E; i += stride) atomicAdd(&deg[dst[i]], 1);
}

// ---- 3-kernel exclusive scan of deg -> rowptr, fused dis = rsqrt(deg+1) ----
__global__ __launch_bounds__(256) void scan_part(const int* __restrict__ deg,
                                                 int* __restrict__ bsum, int N) {
    const int t = threadIdx.x;
    const int i = blockIdx.x * SCHUNK + t * 4;
    int4 v = make_int4(0, 0, 0, 0);
    if (i + 3 < N) v = *(const int4*)(deg + i);
    else {
        if (i < N) v.x = deg[i];
        if (i + 1 < N) v.y = deg[i + 1];
        if (i + 2 < N) v.z = deg[i + 2];
    }
    int s = v.x + v.y + v.z + v.w;
#pragma unroll
    for (int d = 1; d < 64; d <<= 1) s += __shfl_xor(s, d);
    __shared__ int ws[4];
    if ((t & 63) == 0) ws[t >> 6] = s;
    __syncthreads();
    if (t == 0) bsum[blockIdx.x] = ws[0] + ws[1] + ws[2] + ws[3];
}

__global__ __launch_bounds__(128) void scan_top(int* __restrict__ bsum, int NB) {
    __shared__ int sm[128];
    const int t = threadIdx.x;
    const int v = (t < NB) ? bsum[t] : 0;
    sm[t] = v;
    __syncthreads();
    for (int d = 1; d < 128; d <<= 1) {
        int a = (t >= d) ? sm[t - d] : 0;
        __syncthreads();
        sm[t] += a;
        __syncthreads();
    }
    if (t < NB) bsum[t] = sm[t] - v;  // exclusive
}

__global__ __launch_bounds__(256) void scan_write(const int* __restrict__ deg,
                                                  const int* __restrict__ bsum,
                                                  int* __restrict__ rowptr,
                                                  float* __restrict__ dis,
                                                  int N, int NB) {
    const int t = threadIdx.x;
    const int i = blockIdx.x * SCHUNK + t * 4;
    int4 v = make_int4(0, 0, 0, 0);
    if (i + 3 < N) v = *(const int4*)(deg + i);
    else {
        if (i < N) v.x = deg[i];
        if (i + 1 < N) v.y = deg[i + 1];
        if (i + 2 < N) v.z = deg[i + 2];
    }
    const int s = v.x + v.y + v.z + v.w;
    __shared__ int sm[256];
    sm[t] = s;
    __syncthreads();
    for (int d = 1; d < 256; d <<= 1) {
        int a = (t >= d) ? sm[t - d] : 0;
        __syncthreads();
        sm[t] += a;
        __syncthreads();
    }
    int run = bsum[blockIdx.x] + sm[t] - s;
    const int dv[4] = {v.x, v.y, v.z, v.w};
#pragma unroll
    for (int j = 0; j < 4; ++j) {
        if (i + j < N) {
            rowptr[i + j] = run;
            dis[i + j] = rsqrtf((float)dv[j] + 1.0f);
        }
        run += dv[j];
    }
    if (blockIdx.x == NB - 1 && t == 255) rowptr[N] = run;  // == E
}

__global__ __launch_bounds__(256) void csr_fill(const int* __restrict__ src,
                                                const int* __restrict__ dst,
                                                const int* __restrict__ rowptr,
                                                int* __restrict__ fill,
                                                int* __restrict__ col, int E) {
    int i = blockIdx.x * blockDim.x + threadIdx.x;
    int stride = gridDim.x * blockDim.x;
    for (; i < E; i += stride) {
        const int d = dst[i];
        const int pos = rowptr[d] + atomicAdd(&fill[d], 1);
        col[pos] = src[i];
    }
}

// One-time weight pack: W [K][BN] f32 -> hi/lo bf16 in MFMA fragment order.
// packX[((ks*NF + nf)*64 + lane)*8 + e] = W[ks*32 + (lane>>4)*8 + e][nf*16 + (lane&15)]
__global__ __launch_bounds__(256) void pack_w(const float* __restrict__ W,
                                              unsigned short* __restrict__ packH,
                                              unsigned short* __restrict__ packL,
                                              int K, int BN) {
    const int idx = blockIdx.x * blockDim.x + threadIdx.x;
    if (idx >= K * BN) return;
    const int e = idx & 7;
    const int l = (idx >> 3) & 63;
    const int rest = idx >> 9;  // ks*NF + nf
    const int NF = BN >> 4;
    const int nf = rest % NF;
    const int ks = rest / NF;
    const int n = nf * 16 + (l & 15);
    const int k = ks * 32 + ((l >> 4) & 3) * 8 + e;
    const float v = W[(size_t)k * BN + n];
    const unsigned short h = f2bf(v);
    packH[idx] = h;
    packL[idx] = f2bf(v - bf2f(h));
}

// MFMA split-bf16 GEMM: A [N][K] f32 row-major, W pre-packed fragments,
// Out [N][BN]. Block = 128 rows x BN. K % 32 == 0.
template <int BN>
__global__ __launch_bounds__(256) void gemm_mfma(const float* __restrict__ A,
                                                 const unsigned short* __restrict__ WpH,
                                                 const unsigned short* __restrict__ WpL,
                                                 float* __restrict__ Out,
                                                 int N, int K) {
    constexpr int BM = 128;
    constexpr int WROWS = (BN == 128) ? 2 : 4;
    constexpr int WCOLS = (BN == 128) ? 2 : 1;
    constexpr int WTM = BM / WROWS;   // 64 or 32
    constexpr int MF = WTM / 16;      // 4 or 2
    constexpr int NFW = (BN / WCOLS) / 16;  // 4
    constexpr int NFB = BN / 16;      // 8 or 4

    // A tile, fragment-packed: [m-frag 0..7][lane 0..63][8 shorts]
    __shared__ unsigned short AsH[8][512];
    __shared__ unsigned short AsL[8][512];

    const int t = threadIdx.x;
    const int wid = t >> 6, lane = t & 63;
    const int wr = wid / WCOLS, wc = wid % WCOLS;
    const int r0 = blockIdx.x * BM;

    // staging geometry: unit u -> row = u>>2 (0..127), kg = u&3 (8 k each)
    const int s_row1 = t >> 2;          // rows 0..63   (m = wid)
    const int s_row2 = (t + 256) >> 2;  // rows 64..127 (m = 4 + wid)
    const int s_kg = t & 3;
    const int s_lf = ((t >> 2) & 15) + s_kg * 16;  // bijective lane_f per wave

    f32x4 acc[MF][NFW];
#pragma unroll
    for (int m = 0; m < MF; ++m)
#pragma unroll
        for (int n = 0; n < NFW; ++n) acc[m][n] = (f32x4){0.f, 0.f, 0.f, 0.f};

    for (int k0 = 0; k0 < K; k0 += 32) {
        const int ks = k0 >> 5;
        // ---- stage A (two units per thread), conflict-free packed writes ----
#pragma unroll
        for (int uu = 0; uu < 2; ++uu) {
            const int row = uu ? s_row2 : s_row1;
            const int gr = r0 + row;
            float4 v0 = make_float4(0.f, 0.f, 0.f, 0.f), v1 = v0;
            if (gr < N) {
                const float* ap = &A[(size_t)gr * K + k0 + s_kg * 8];
                v0 = *(const float4*)ap;
                v1 = *(const float4*)(ap + 4);
            }
            short8 h, l;
            const float vv[8] = {v0.x, v0.y, v0.z, v0.w, v1.x, v1.y, v1.z, v1.w};
#pragma unroll
            for (int j = 0; j < 8; ++j) {
                const unsigned short hh = f2bf(vv[j]);
                h[j] = (short)hh;
                l[j] = (short)f2bf(vv[j] - bf2f(hh));
            }
            const int m = row >> 4;
            *(short8*)&AsH[m][s_lf * 8] = h;
            *(short8*)&AsL[m][s_lf * 8] = l;
        }
        __syncthreads();

        // ---- B fragments straight from packed global (L2-hit, coalesced) ----
        short8 bH[NFW], bL[NFW];
#pragma unroll
        for (int n = 0; n < NFW; ++n) {
            const int nfg = wc * NFW + n;
            const int base = ((ks * NFB + nfg) * 64 + lane) * 8;
            bH[n] = *(const short8*)&WpH[base];
            bL[n] = *(const short8*)&WpL[base];
        }
        // ---- MFMA ----
#pragma unroll
        for (int m = 0; m < MF; ++m) {
            const int mf = wr * MF + m;
            const short8 aH = *(const short8*)&AsH[mf][lane * 8];
            const short8 aL = *(const short8*)&AsL[mf][lane * 8];
#pragma unroll
            for (int n = 0; n < NFW; ++n) {
                acc[m][n] = __builtin_amdgcn_mfma_f32_16x16x32_bf16(aH, bH[n], acc[m][n], 0, 0, 0);
                acc[m][n] = __builtin_amdgcn_mfma_f32_16x16x32_bf16(aH, bL[n], acc[m][n], 0, 0, 0);
                acc[m][n] = __builtin_amdgcn_mfma_f32_16x16x32_bf16(aL, bH[n], acc[m][n], 0, 0, 0);
            }
        }
        __syncthreads();
    }

    // ---- C write: D[(lane>>4)*4 + r][lane&15] per fragment ----
#pragma unroll
    for (int m = 0; m < MF; ++m) {
#pragma unroll
        for (int n = 0; n < NFW; ++n) {
            const int row0 = r0 + wr * WTM + m * 16 + ((lane >> 4) << 2);
            const int cn = wc * (NFW * 16) + n * 16 + (lane & 15);
#pragma unroll
            for (int r = 0; r < 4; ++r) {
                if (row0 + r < N) Out[(size_t)(row0 + r) * BN + cn] = acc[m][n][r];
            }
        }
    }
}

// CSR gather aggregation, one wave per dst node.
template <int COLS>
__global__ __launch_bounds__(256) void agg_csr(const int* __restrict__ rowptr,
                                               const int* __restrict__ col,
                                               const float* __restrict__ dis,
                                               const float* __restrict__ H,
                                               const float* __restrict__ bias,
                                               float* __restrict__ Out, int N) {
    constexpr int VPL = COLS / 64;
    const int wid = (int)((blockIdx.x * blockDim.x + threadIdx.x) >> 6);
    const int lane = threadIdx.x & 63;
    if (wid >= N) return;
    const int node = wid;
    const int base = rowptr[node];
    const int len = rowptr[node + 1] - base;

    float acc[VPL];
#pragma unroll
    for (int v = 0; v < VPL; ++v) acc[v] = 0.f;

    for (int j0 = 0; j0 < len; j0 += 64) {
        const int remain = min(64, len - j0);
        const int sidx = (lane < remain) ? col[base + j0 + lane] : 0;
        const float sw = (lane < remain) ? dis[sidx] : 0.f;
        for (int j = 0; j < remain; ++j) {
            const int s = __shfl(sidx, j);
            const float w = __shfl(sw, j);
            const float* hp = H + (size_t)s * COLS + lane * VPL;
            if (VPL == 2) {
                const float2 hv = *(const float2*)hp;
                acc[0] = fmaf(hv.x, w, acc[0]);
                acc[1] = fmaf(hv.y, w, acc[1]);
            } else {
                acc[0] = fmaf(hp[0], w, acc[0]);
            }
        }
    }

    const float dd = dis[node];
    const float* hself = H + (size_t)node * COLS + lane * VPL;
    float* outp = Out + (size_t)node * COLS + lane * VPL;
#pragma unroll
    for (int v = 0; v < VPL; ++v) {
        const float r = fmaf(acc[v], dd, hself[v] * dd * dd) + bias[lane * VPL + v];
        outp[v] = fmaxf(r, 0.f);
    }
}

__global__ __launch_bounds__(256) void pool_kernel(const float* __restrict__ H,
                                                   const int* __restrict__ batch,
                                                   float* __restrict__ pooled,
                                                   float* __restrict__ cnt, int N) {
    constexpr int CHUNK = 1024;
    const int n0 = blockIdx.x * CHUNK;
    const int c = threadIdx.x & 63;
    const int r = threadIdx.x >> 6;
    int curg = -1;
    float sum = 0.f, csum = 0.f;
    for (int i = r; i < CHUNK; i += 4) {
        const int n = n0 + i;
        if (n >= N) break;
        const int g = batch[n];
        if (g != curg) {
            if (curg >= 0) {
                atomicAdd(&pooled[curg * 64 + c], sum);
                if (c == 0) atomicAdd(&cnt[curg], csum);
            }
            curg = g;
            sum = 0.f;
            csum = 0.f;
        }
        sum += H[(size_t)n * 64 + c];
        csum += 1.f;
    }
    if (curg >= 0) {
        atomicAdd(&pooled[curg * 64 + c], sum);
        if (c == 0) atomicAdd(&cnt[curg], csum);
    }
}

__global__ __launch_bounds__(256) void final_kernel(const float* __restrict__ pooled,
                                                    const float* __restrict__ cnt,
                                                    const float* __restrict__ Wlin,
                                                    const float* __restrict__ blin,
                                                    float* __restrict__ out) {
    const int t = threadIdx.x;
    const int g = t >> 1, o = t & 1;
    const float inv = 1.0f / fmaxf(cnt[g], 1.0f);
    float s = 0.f;
#pragma unroll
    for (int j = 0; j < 64; ++j) s = fmaf(pooled[g * 64 + j], Wlin[j * 2 + o], s);
    out[t] = s * inv + blin[o];
}

extern "C" void kernel_launch(void* const* d_in, const int* in_sizes, int n_in,
                              void* d_out, int out_size, void* d_ws, size_t ws_size,
                              hipStream_t stream) {
    const float* x     = (const float*)d_in[0];
    const int*   edge  = (const int*)d_in[1];
    const int*   batch = (const int*)d_in[2];
    const float* W1    = (const float*)d_in[3];
    const float* b1    = (const float*)d_in[4];
    const float* W2    = (const float*)d_in[5];
    const float* b2    = (const float*)d_in[6];
    const float* Wlin  = (const float*)d_in[7];
    const float* blin  = (const float*)d_in[8];
    float* out = (float*)d_out;

    const int N = NN;
    const int E = in_sizes[1] / 2;
    const int* src = edge;
    const int* dst = edge + E;
    const int NB = (N + SCHUNK - 1) / SCHUNK;  // 98

    char* ws = (char*)d_ws;
    size_t off = 0;
    auto alloc = [&](size_t bytes) -> void* {
        void* p = ws + off;
        off += (bytes + 511) & ~(size_t)511;
        return p;
    };
    int*   deg    = (int*)alloc((size_t)N * 4);
    float* dis    = (float*)alloc((size_t)N * 4);
    int*   rowptr = (int*)alloc((size_t)(N + 1) * 4);
    int*   fill   = (int*)alloc((size_t)N * 4);
    int*   bsum   = (int*)alloc((size_t)NB * 4);
    int*   col    = (int*)alloc((size_t)E * 4);
    unsigned short* w1h = (unsigned short*)alloc((size_t)384 * 128 * 2);
    unsigned short* w1l = (unsigned short*)alloc((size_t)384 * 128 * 2);
    unsigned short* w2h = (unsigned short*)alloc((size_t)128 * 64 * 2);
    unsigned short* w2l = (unsigned short*)alloc((size_t)128 * 64 * 2);
    float* h1     = (float*)alloc((size_t)N * 128 * 4);
    float* agg1   = (float*)alloc((size_t)N * 128 * 4);
    float* pooled = (float*)alloc((size_t)NG * 64 * 4);
    float* cnt    = (float*)alloc((size_t)NG * 4);
    float* h2   = h1;
    float* agg2 = (float*)((char*)h1 + (size_t)N * 64 * 4);

    hipMemsetAsync(deg, 0, (size_t)N * 4, stream);
    hipMemsetAsync(fill, 0, (size_t)N * 4, stream);
    hipMemsetAsync(pooled, 0, (size_t)NG * 64 * 4, stream);
    hipMemsetAsync(cnt, 0, (size_t)NG * 4, stream);

    // weight packing (tiny, once per call)
    pack_w<<<(384 * 128 + 255) / 256, 256, 0, stream>>>(W1, w1h, w1l, 384, 128);
    pack_w<<<(128 * 64 + 255) / 256, 256, 0, stream>>>(W2, w2h, w2l, 128, 64);

    // degree + CSR build + normalization
    deg_kernel<<<2048, 256, 0, stream>>>(dst, deg, E);
    scan_part<<<NB, 256, 0, stream>>>(deg, bsum, N);
    scan_top<<<1, 128, 0, stream>>>(bsum, NB);
    scan_write<<<NB, 256, 0, stream>>>(deg, bsum, rowptr, dis, N, NB);
    csr_fill<<<2048, 256, 0, stream>>>(src, dst, rowptr, fill, col, E);

    const int gblocks = (N + 127) / 128;
    // layer 1
    gemm_mfma<128><<<gblocks, 256, 0, stream>>>(x, w1h, w1l, h1, N, 384);
    agg_csr<128><<<(N + 3) / 4, 256, 0, stream>>>(rowptr, col, dis, h1, b1, agg1, N);

    // layer 2
    gemm_mfma<64><<<gblocks, 256, 0, stream>>>(agg1, w2h, w2l, h2, N, 128);
    agg_csr<64><<<(N + 3) / 4, 256, 0, stream>>>(rowptr, col, dis, h2, b2, agg2, N);

    // pool + head
    pool_kernel<<<(N + 1023) / 1024, 256, 0, stream>>>(agg2, batch, pooled, cnt, N);
    final_kernel<<<1, 256, 0, stream>>>(pooled, cnt, Wlin, blin, out);
}

// Round 6
// 560.941 us; speedup vs baseline: 8.2384x; 1.0981x over previous
//
#include <hip/hip_runtime.h>

// GCN 2-layer + mean-pool + linear head, f32.
// Round 6: agg_csr was latency-bound (VALU 20%, HBM 45%, VGPR=12 -> ~1
// outstanding load/wave). Fix MLP:
//   - inner edge loop unrolled x8: 8 independent float2 gathers in flight
//   - COLS=64 packs 2 nodes/wave (32 lanes x float2) -> 8B/lane loads
// GEMMs (fragment-packed MFMA split-bf16), scan, CSR build unchanged.

#define NN 100000
#define NG 128
#define SCHUNK 1024

typedef __attribute__((ext_vector_type(8))) short short8;
typedef __attribute__((ext_vector_type(4))) float f32x4;

__device__ __forceinline__ unsigned short f2bf(float f) {
    union { float f; unsigned u; } v; v.f = f;
    unsigned r = v.u + 0x7fffu + ((v.u >> 16) & 1u);  // round-nearest-even
    return (unsigned short)(r >> 16);
}
__device__ __forceinline__ float bf2f(unsigned short h) {
    union { unsigned u; float f; } v; v.u = ((unsigned)h) << 16;
    return v.f;
}

__global__ __launch_bounds__(256) void deg_kernel(const int* __restrict__ dst,
                                                  int* __restrict__ deg, int E) {
    int i = blockIdx.x * blockDim.x + threadIdx.x;
    int stride = gridDim.x * blockDim.x;
    for (; i < E; i += stride) atomicAdd(&deg[dst[i]], 1);
}

// ---- 3-kernel exclusive scan of deg -> rowptr, fused dis = rsqrt(deg+1) ----
__global__ __launch_bounds__(256) void scan_part(const int* __restrict__ deg,
                                                 int* __restrict__ bsum, int N) {
    const int t = threadIdx.x;
    const int i = blockIdx.x * SCHUNK + t * 4;
    int4 v = make_int4(0, 0, 0, 0);
    if (i + 3 < N) v = *(const int4*)(deg + i);
    else {
        if (i < N) v.x = deg[i];
        if (i + 1 < N) v.y = deg[i + 1];
        if (i + 2 < N) v.z = deg[i + 2];
    }
    int s = v.x + v.y + v.z + v.w;
#pragma unroll
    for (int d = 1; d < 64; d <<= 1) s += __shfl_xor(s, d);
    __shared__ int ws[4];
    if ((t & 63) == 0) ws[t >> 6] = s;
    __syncthreads();
    if (t == 0) bsum[blockIdx.x] = ws[0] + ws[1] + ws[2] + ws[3];
}

__global__ __launch_bounds__(128) void scan_top(int* __restrict__ bsum, int NB) {
    __shared__ int sm[128];
    const int t = threadIdx.x;
    const int v = (t < NB) ? bsum[t] : 0;
    sm[t] = v;
    __syncthreads();
    for (int d = 1; d < 128; d <<= 1) {
        int a = (t >= d) ? sm[t - d] : 0;
        __syncthreads();
        sm[t] += a;
        __syncthreads();
    }
    if (t < NB) bsum[t] = sm[t] - v;  // exclusive
}

__global__ __launch_bounds__(256) void scan_write(const int* __restrict__ deg,
                                                  const int* __restrict__ bsum,
                                                  int* __restrict__ rowptr,
                                                  float* __restrict__ dis,
                                                  int N, int NB) {
    const int t = threadIdx.x;
    const int i = blockIdx.x * SCHUNK + t * 4;
    int4 v = make_int4(0, 0, 0, 0);
    if (i + 3 < N) v = *(const int4*)(deg + i);
    else {
        if (i < N) v.x = deg[i];
        if (i + 1 < N) v.y = deg[i + 1];
        if (i + 2 < N) v.z = deg[i + 2];
    }
    const int s = v.x + v.y + v.z + v.w;
    __shared__ int sm[256];
    sm[t] = s;
    __syncthreads();
    for (int d = 1; d < 256; d <<= 1) {
        int a = (t >= d) ? sm[t - d] : 0;
        __syncthreads();
        sm[t] += a;
        __syncthreads();
    }
    int run = bsum[blockIdx.x] + sm[t] - s;
    const int dv[4] = {v.x, v.y, v.z, v.w};
#pragma unroll
    for (int j = 0; j < 4; ++j) {
        if (i + j < N) {
            rowptr[i + j] = run;
            dis[i + j] = rsqrtf((float)dv[j] + 1.0f);
        }
        run += dv[j];
    }
    if (blockIdx.x == NB - 1 && t == 255) rowptr[N] = run;  // == E
}

__global__ __launch_bounds__(256) void csr_fill(const int* __restrict__ src,
                                                const int* __restrict__ dst,
                                                const int* __restrict__ rowptr,
                                                int* __restrict__ fill,
                                                int* __restrict__ col, int E) {
    int i = blockIdx.x * blockDim.x + threadIdx.x;
    int stride = gridDim.x * blockDim.x;
    for (; i < E; i += stride) {
        const int d = dst[i];
        const int pos = rowptr[d] + atomicAdd(&fill[d], 1);
        col[pos] = src[i];
    }
}

// One-time weight pack: W [K][BN] f32 -> hi/lo bf16 in MFMA fragment order.
__global__ __launch_bounds__(256) void pack_w(const float* __restrict__ W,
                                              unsigned short* __restrict__ packH,
                                              unsigned short* __restrict__ packL,
                                              int K, int BN) {
    const int idx = blockIdx.x * blockDim.x + threadIdx.x;
    if (idx >= K * BN) return;
    const int e = idx & 7;
    const int l = (idx >> 3) & 63;
    const int rest = idx >> 9;  // ks*NF + nf
    const int NF = BN >> 4;
    const int nf = rest % NF;
    const int ks = rest / NF;
    const int n = nf * 16 + (l & 15);
    const int k = ks * 32 + ((l >> 4) & 3) * 8 + e;
    const float v = W[(size_t)k * BN + n];
    const unsigned short h = f2bf(v);
    packH[idx] = h;
    packL[idx] = f2bf(v - bf2f(h));
}

// MFMA split-bf16 GEMM: A [N][K] f32 row-major, W pre-packed fragments.
template <int BN>
__global__ __launch_bounds__(256) void gemm_mfma(const float* __restrict__ A,
                                                 const unsigned short* __restrict__ WpH,
                                                 const unsigned short* __restrict__ WpL,
                                                 float* __restrict__ Out,
                                                 int N, int K) {
    constexpr int BM = 128;
    constexpr int WROWS = (BN == 128) ? 2 : 4;
    constexpr int WCOLS = (BN == 128) ? 2 : 1;
    constexpr int WTM = BM / WROWS;
    constexpr int MF = WTM / 16;
    constexpr int NFW = (BN / WCOLS) / 16;
    constexpr int NFB = BN / 16;

    __shared__ unsigned short AsH[8][512];
    __shared__ unsigned short AsL[8][512];

    const int t = threadIdx.x;
    const int wid = t >> 6, lane = t & 63;
    const int wr = wid / WCOLS, wc = wid % WCOLS;
    const int r0 = blockIdx.x * BM;

    const int s_row1 = t >> 2;
    const int s_row2 = (t + 256) >> 2;
    const int s_kg = t & 3;
    const int s_lf = ((t >> 2) & 15) + s_kg * 16;

    f32x4 acc[MF][NFW];
#pragma unroll
    for (int m = 0; m < MF; ++m)
#pragma unroll
        for (int n = 0; n < NFW; ++n) acc[m][n] = (f32x4){0.f, 0.f, 0.f, 0.f};

    for (int k0 = 0; k0 < K; k0 += 32) {
        const int ks = k0 >> 5;
#pragma unroll
        for (int uu = 0; uu < 2; ++uu) {
            const int row = uu ? s_row2 : s_row1;
            const int gr = r0 + row;
            float4 v0 = make_float4(0.f, 0.f, 0.f, 0.f), v1 = v0;
            if (gr < N) {
                const float* ap = &A[(size_t)gr * K + k0 + s_kg * 8];
                v0 = *(const float4*)ap;
                v1 = *(const float4*)(ap + 4);
            }
            short8 h, l;
            const float vv[8] = {v0.x, v0.y, v0.z, v0.w, v1.x, v1.y, v1.z, v1.w};
#pragma unroll
            for (int j = 0; j < 8; ++j) {
                const unsigned short hh = f2bf(vv[j]);
                h[j] = (short)hh;
                l[j] = (short)f2bf(vv[j] - bf2f(hh));
            }
            const int m = row >> 4;
            *(short8*)&AsH[m][s_lf * 8] = h;
            *(short8*)&AsL[m][s_lf * 8] = l;
        }
        __syncthreads();

        short8 bH[NFW], bL[NFW];
#pragma unroll
        for (int n = 0; n < NFW; ++n) {
            const int nfg = wc * NFW + n;
            const int base = ((ks * NFB + nfg) * 64 + lane) * 8;
            bH[n] = *(const short8*)&WpH[base];
            bL[n] = *(const short8*)&WpL[base];
        }
#pragma unroll
        for (int m = 0; m < MF; ++m) {
            const int mf = wr * MF + m;
            const short8 aH = *(const short8*)&AsH[mf][lane * 8];
            const short8 aL = *(const short8*)&AsL[mf][lane * 8];
#pragma unroll
            for (int n = 0; n < NFW; ++n) {
                acc[m][n] = __builtin_amdgcn_mfma_f32_16x16x32_bf16(aH, bH[n], acc[m][n], 0, 0, 0);
                acc[m][n] = __builtin_amdgcn_mfma_f32_16x16x32_bf16(aH, bL[n], acc[m][n], 0, 0, 0);
                acc[m][n] = __builtin_amdgcn_mfma_f32_16x16x32_bf16(aL, bH[n], acc[m][n], 0, 0, 0);
            }
        }
        __syncthreads();
    }

#pragma unroll
    for (int m = 0; m < MF; ++m) {
#pragma unroll
        for (int n = 0; n < NFW; ++n) {
            const int row0 = r0 + wr * WTM + m * 16 + ((lane >> 4) << 2);
            const int cn = wc * (NFW * 16) + n * 16 + (lane & 15);
#pragma unroll
            for (int r = 0; r < 4; ++r) {
                if (row0 + r < N) Out[(size_t)(row0 + r) * BN + cn] = acc[m][n][r];
            }
        }
    }
}

// CSR gather aggregation. NPW nodes per wave, 64/NPW lanes per node,
// float2 per lane. Inner edge loop unrolled x8 for MLP.
template <int COLS, int NPW>
__global__ __launch_bounds__(256) void agg_csr(const int* __restrict__ rowptr,
                                               const int* __restrict__ col,
                                               const float* __restrict__ dis,
                                               const float* __restrict__ H,
                                               const float* __restrict__ bias,
                                               float* __restrict__ Out, int N) {
    constexpr int LPN = 64 / NPW;        // lanes per node
    static_assert(COLS == LPN * 2, "float2 per lane");
    const int gw = (int)((blockIdx.x * blockDim.x + threadIdx.x) >> 6);
    const int lane = threadIdx.x & 63;
    const int sub = lane / LPN;
    const int sl = lane % LPN;
    const int lbase = sub * LPN;
    const int node = gw * NPW + sub;

    float acc0 = 0.f, acc1 = 0.f;
    int base = 0, len = 0;
    if (node < N) {
        base = rowptr[node];
        len = rowptr[node + 1] - base;
    }

    for (int j0 = 0; j0 < len; j0 += LPN) {
        const int remain = min(LPN, len - j0);
        const int sidx = (sl < remain) ? col[base + j0 + sl] : 0;
        const float sw = (sl < remain) ? dis[sidx] : 0.f;
        int j = 0;
        for (; j + 8 <= remain; j += 8) {
            float2 hv[8];
            float w8[8];
#pragma unroll
            for (int u = 0; u < 8; ++u) {
                const int s = __shfl(sidx, lbase + j + u);
                w8[u] = __shfl(sw, lbase + j + u);
                hv[u] = *(const float2*)(H + (size_t)s * COLS + sl * 2);
            }
#pragma unroll
            for (int u = 0; u < 8; ++u) {
                acc0 = fmaf(hv[u].x, w8[u], acc0);
                acc1 = fmaf(hv[u].y, w8[u], acc1);
            }
        }
        for (; j < remain; ++j) {
            const int s = __shfl(sidx, lbase + j);
            const float w = __shfl(sw, lbase + j);
            const float2 hv = *(const float2*)(H + (size_t)s * COLS + sl * 2);
            acc0 = fmaf(hv.x, w, acc0);
            acc1 = fmaf(hv.y, w, acc1);
        }
    }

    if (node < N) {
        const float dd = dis[node];
        const float2 hs = *(const float2*)(H + (size_t)node * COLS + sl * 2);
        const float2 bv = *(const float2*)(bias + sl * 2);
        float2 o;
        o.x = fmaxf(fmaf(acc0, dd, hs.x * dd * dd) + bv.x, 0.f);
        o.y = fmaxf(fmaf(acc1, dd, hs.y * dd * dd) + bv.y, 0.f);
        *(float2*)(Out + (size_t)node * COLS + sl * 2) = o;
    }
}

__global__ __launch_bounds__(256) void pool_kernel(const float* __restrict__ H,
                                                   const int* __restrict__ batch,
                                                   float* __restrict__ pooled,
                                                   float* __restrict__ cnt, int N) {
    constexpr int CHUNK = 1024;
    const int n0 = blockIdx.x * CHUNK;
    const int c = threadIdx.x & 63;
    const int r = threadIdx.x >> 6;
    int curg = -1;
    float sum = 0.f, csum = 0.f;
    for (int i = r; i < CHUNK; i += 4) {
        const int n = n0 + i;
        if (n >= N) break;
        const int g = batch[n];
        if (g != curg) {
            if (curg >= 0) {
                atomicAdd(&pooled[curg * 64 + c], sum);
                if (c == 0) atomicAdd(&cnt[curg], csum);
            }
            curg = g;
            sum = 0.f;
            csum = 0.f;
        }
        sum += H[(size_t)n * 64 + c];
        csum += 1.f;
    }
    if (curg >= 0) {
        atomicAdd(&pooled[curg * 64 + c], sum);
        if (c == 0) atomicAdd(&cnt[curg], csum);
    }
}

__global__ __launch_bounds__(256) void final_kernel(const float* __restrict__ pooled,
                                                    const float* __restrict__ cnt,
                                                    const float* __restrict__ Wlin,
                                                    const float* __restrict__ blin,
                                                    float* __restrict__ out) {
    const int t = threadIdx.x;
    const int g = t >> 1, o = t & 1;
    const float inv = 1.0f / fmaxf(cnt[g], 1.0f);
    float s = 0.f;
#pragma unroll
    for (int j = 0; j < 64; ++j) s = fmaf(pooled[g * 64 + j], Wlin[j * 2 + o], s);
    out[t] = s * inv + blin[o];
}

extern "C" void kernel_launch(void* const* d_in, const int* in_sizes, int n_in,
                              void* d_out, int out_size, void* d_ws, size_t ws_size,
                              hipStream_t stream) {
    const float* x     = (const float*)d_in[0];
    const int*   edge  = (const int*)d_in[1];
    const int*   batch = (const int*)d_in[2];
    const float* W1    = (const float*)d_in[3];
    const float* b1    = (const float*)d_in[4];
    const float* W2    = (const float*)d_in[5];
    const float* b2    = (const float*)d_in[6];
    const float* Wlin  = (const float*)d_in[7];
    const float* blin  = (const float*)d_in[8];
    float* out = (float*)d_out;

    const int N = NN;
    const int E = in_sizes[1] / 2;
    const int* src = edge;
    const int* dst = edge + E;
    const int NB = (N + SCHUNK - 1) / SCHUNK;  // 98

    char* ws = (char*)d_ws;
    size_t off = 0;
    auto alloc = [&](size_t bytes) -> void* {
        void* p = ws + off;
        off += (bytes + 511) & ~(size_t)511;
        return p;
    };
    int*   deg    = (int*)alloc((size_t)N * 4);
    float* dis    = (float*)alloc((size_t)N * 4);
    int*   rowptr = (int*)alloc((size_t)(N + 1) * 4);
    int*   fill   = (int*)alloc((size_t)N * 4);
    int*   bsum   = (int*)alloc((size_t)NB * 4);
    int*   col    = (int*)alloc((size_t)E * 4);
    unsigned short* w1h = (unsigned short*)alloc((size_t)384 * 128 * 2);
    unsigned short* w1l = (unsigned short*)alloc((size_t)384 * 128 * 2);
    unsigned short* w2h = (unsigned short*)alloc((size_t)128 * 64 * 2);
    unsigned short* w2l = (unsigned short*)alloc((size_t)128 * 64 * 2);
    float* h1     = (float*)alloc((size_t)N * 128 * 4);
    float* agg1   = (float*)alloc((size_t)N * 128 * 4);
    float* pooled = (float*)alloc((size_t)NG * 64 * 4);
    float* cnt    = (float*)alloc((size_t)NG * 4);
    float* h2   = h1;
    float* agg2 = (float*)((char*)h1 + (size_t)N * 64 * 4);

    hipMemsetAsync(deg, 0, (size_t)N * 4, stream);
    hipMemsetAsync(fill, 0, (size_t)N * 4, stream);
    hipMemsetAsync(pooled, 0, (size_t)NG * 64 * 4, stream);
    hipMemsetAsync(cnt, 0, (size_t)NG * 4, stream);

    // weight packing (tiny, once per call)
    pack_w<<<(384 * 128 + 255) / 256, 256, 0, stream>>>(W1, w1h, w1l, 384, 128);
    pack_w<<<(128 * 64 + 255) / 256, 256, 0, stream>>>(W2, w2h, w2l, 128, 64);

    // degree + CSR build + normalization
    deg_kernel<<<2048, 256, 0, stream>>>(dst, deg, E);
    scan_part<<<NB, 256, 0, stream>>>(deg, bsum, N);
    scan_top<<<1, 128, 0, stream>>>(bsum, NB);
    scan_write<<<NB, 256, 0, stream>>>(deg, bsum, rowptr, dis, N, NB);
    csr_fill<<<2048, 256, 0, stream>>>(src, dst, rowptr, fill, col, E);

    const int gblocks = (N + 127) / 128;
    // layer 1
    gemm_mfma<128><<<gblocks, 256, 0, stream>>>(x, w1h, w1l, h1, N, 384);
    agg_csr<128, 1><<<(N + 3) / 4, 256, 0, stream>>>(rowptr, col, dis, h1, b1, agg1, N);

    // layer 2
    gemm_mfma<64><<<gblocks, 256, 0, stream>>>(agg1, w2h, w2l, h2, N, 128);
    agg_csr<64, 2><<<(N + 7) / 8, 256, 0, stream>>>(rowptr, col, dis, h2, b2, agg2, N);

    // pool + head
    pool_kernel<<<(N + 1023) / 1024, 256, 0, stream>>>(agg2, batch, pooled, cnt, N);
    final_kernel<<<1, 256, 0, stream>>>(pooled, cnt, Wlin, blin, out);
}

// Round 7
// 453.197 us; speedup vs baseline: 10.1971x; 1.2377x over previous
//
#include <hip/hip_runtime.h>

// GCN 2-layer + mean-pool + linear head, f32.
// Round 7: pool_kernel was grid-starved (98 blocks, 3.8% occ, 103 GB/s).
//   New pool: 782 blocks, wave = 32 consecutive rows, lane = column,
//   32 unrolled independent loads into regs, then register run-length
//   accumulate, ~1 atomic/lane/strip (~200k atomics on L2-resident 32KB).
// GEMMs (fragment-packed MFMA split-bf16), agg_csr (x8 MLP unroll),
// scan + CSR build unchanged from round 6.

#define NN 100000
#define NG 128
#define SCHUNK 1024

typedef __attribute__((ext_vector_type(8))) short short8;
typedef __attribute__((ext_vector_type(4))) float f32x4;

__device__ __forceinline__ unsigned short f2bf(float f) {
    union { float f; unsigned u; } v; v.f = f;
    unsigned r = v.u + 0x7fffu + ((v.u >> 16) & 1u);  // round-nearest-even
    return (unsigned short)(r >> 16);
}
__device__ __forceinline__ float bf2f(unsigned short h) {
    union { unsigned u; float f; } v; v.u = ((unsigned)h) << 16;
    return v.f;
}

__global__ __launch_bounds__(256) void deg_kernel(const int* __restrict__ dst,
                                                  int* __restrict__ deg, int E) {
    int i = blockIdx.x * blockDim.x + threadIdx.x;
    int stride = gridDim.x * blockDim.x;
    for (; i < E; i += stride) atomicAdd(&deg[dst[i]], 1);
}

// ---- 3-kernel exclusive scan of deg -> rowptr, fused dis = rsqrt(deg+1) ----
__global__ __launch_bounds__(256) void scan_part(const int* __restrict__ deg,
                                                 int* __restrict__ bsum, int N) {
    const int t = threadIdx.x;
    const int i = blockIdx.x * SCHUNK + t * 4;
    int4 v = make_int4(0, 0, 0, 0);
    if (i + 3 < N) v = *(const int4*)(deg + i);
    else {
        if (i < N) v.x = deg[i];
        if (i + 1 < N) v.y = deg[i + 1];
        if (i + 2 < N) v.z = deg[i + 2];
    }
    int s = v.x + v.y + v.z + v.w;
#pragma unroll
    for (int d = 1; d < 64; d <<= 1) s += __shfl_xor(s, d);
    __shared__ int ws[4];
    if ((t & 63) == 0) ws[t >> 6] = s;
    __syncthreads();
    if (t == 0) bsum[blockIdx.x] = ws[0] + ws[1] + ws[2] + ws[3];
}

__global__ __launch_bounds__(128) void scan_top(int* __restrict__ bsum, int NB) {
    __shared__ int sm[128];
    const int t = threadIdx.x;
    const int v = (t < NB) ? bsum[t] : 0;
    sm[t] = v;
    __syncthreads();
    for (int d = 1; d < 128; d <<= 1) {
        int a = (t >= d) ? sm[t - d] : 0;
        __syncthreads();
        sm[t] += a;
        __syncthreads();
    }
    if (t < NB) bsum[t] = sm[t] - v;  // exclusive
}

__global__ __launch_bounds__(256) void scan_write(const int* __restrict__ deg,
                                                  const int* __restrict__ bsum,
                                                  int* __restrict__ rowptr,
                                                  float* __restrict__ dis,
                                                  int N, int NB) {
    const int t = threadIdx.x;
    const int i = blockIdx.x * SCHUNK + t * 4;
    int4 v = make_int4(0, 0, 0, 0);
    if (i + 3 < N) v = *(const int4*)(deg + i);
    else {
        if (i < N) v.x = deg[i];
        if (i + 1 < N) v.y = deg[i + 1];
        if (i + 2 < N) v.z = deg[i + 2];
    }
    const int s = v.x + v.y + v.z + v.w;
    __shared__ int sm[256];
    sm[t] = s;
    __syncthreads();
    for (int d = 1; d < 256; d <<= 1) {
        int a = (t >= d) ? sm[t - d] : 0;
        __syncthreads();
        sm[t] += a;
        __syncthreads();
    }
    int run = bsum[blockIdx.x] + sm[t] - s;
    const int dv[4] = {v.x, v.y, v.z, v.w};
#pragma unroll
    for (int j = 0; j < 4; ++j) {
        if (i + j < N) {
            rowptr[i + j] = run;
            dis[i + j] = rsqrtf((float)dv[j] + 1.0f);
        }
        run += dv[j];
    }
    if (blockIdx.x == NB - 1 && t == 255) rowptr[N] = run;  // == E
}

__global__ __launch_bounds__(256) void csr_fill(const int* __restrict__ src,
                                                const int* __restrict__ dst,
                                                const int* __restrict__ rowptr,
                                                int* __restrict__ fill,
                                                int* __restrict__ col, int E) {
    int i = blockIdx.x * blockDim.x + threadIdx.x;
    int stride = gridDim.x * blockDim.x;
    for (; i < E; i += stride) {
        const int d = dst[i];
        const int pos = rowptr[d] + atomicAdd(&fill[d], 1);
        col[pos] = src[i];
    }
}

// One-time weight pack: W [K][BN] f32 -> hi/lo bf16 in MFMA fragment order.
__global__ __launch_bounds__(256) void pack_w(const float* __restrict__ W,
                                              unsigned short* __restrict__ packH,
                                              unsigned short* __restrict__ packL,
                                              int K, int BN) {
    const int idx = blockIdx.x * blockDim.x + threadIdx.x;
    if (idx >= K * BN) return;
    const int e = idx & 7;
    const int l = (idx >> 3) & 63;
    const int rest = idx >> 9;  // ks*NF + nf
    const int NF = BN >> 4;
    const int nf = rest % NF;
    const int ks = rest / NF;
    const int n = nf * 16 + (l & 15);
    const int k = ks * 32 + ((l >> 4) & 3) * 8 + e;
    const float v = W[(size_t)k * BN + n];
    const unsigned short h = f2bf(v);
    packH[idx] = h;
    packL[idx] = f2bf(v - bf2f(h));
}

// MFMA split-bf16 GEMM: A [N][K] f32 row-major, W pre-packed fragments.
template <int BN>
__global__ __launch_bounds__(256) void gemm_mfma(const float* __restrict__ A,
                                                 const unsigned short* __restrict__ WpH,
                                                 const unsigned short* __restrict__ WpL,
                                                 float* __restrict__ Out,
                                                 int N, int K) {
    constexpr int BM = 128;
    constexpr int WROWS = (BN == 128) ? 2 : 4;
    constexpr int WCOLS = (BN == 128) ? 2 : 1;
    constexpr int WTM = BM / WROWS;
    constexpr int MF = WTM / 16;
    constexpr int NFW = (BN / WCOLS) / 16;
    constexpr int NFB = BN / 16;

    __shared__ unsigned short AsH[8][512];
    __shared__ unsigned short AsL[8][512];

    const int t = threadIdx.x;
    const int wid = t >> 6, lane = t & 63;
    const int wr = wid / WCOLS, wc = wid % WCOLS;
    const int r0 = blockIdx.x * BM;

    const int s_row1 = t >> 2;
    const int s_row2 = (t + 256) >> 2;
    const int s_kg = t & 3;
    const int s_lf = ((t >> 2) & 15) + s_kg * 16;

    f32x4 acc[MF][NFW];
#pragma unroll
    for (int m = 0; m < MF; ++m)
#pragma unroll
        for (int n = 0; n < NFW; ++n) acc[m][n] = (f32x4){0.f, 0.f, 0.f, 0.f};

    for (int k0 = 0; k0 < K; k0 += 32) {
        const int ks = k0 >> 5;
#pragma unroll
        for (int uu = 0; uu < 2; ++uu) {
            const int row = uu ? s_row2 : s_row1;
            const int gr = r0 + row;
            float4 v0 = make_float4(0.f, 0.f, 0.f, 0.f), v1 = v0;
            if (gr < N) {
                const float* ap = &A[(size_t)gr * K + k0 + s_kg * 8];
                v0 = *(const float4*)ap;
                v1 = *(const float4*)(ap + 4);
            }
            short8 h, l;
            const float vv[8] = {v0.x, v0.y, v0.z, v0.w, v1.x, v1.y, v1.z, v1.w};
#pragma unroll
            for (int j = 0; j < 8; ++j) {
                const unsigned short hh = f2bf(vv[j]);
                h[j] = (short)hh;
                l[j] = (short)f2bf(vv[j] - bf2f(hh));
            }
            const int m = row >> 4;
            *(short8*)&AsH[m][s_lf * 8] = h;
            *(short8*)&AsL[m][s_lf * 8] = l;
        }
        __syncthreads();

        short8 bH[NFW], bL[NFW];
#pragma unroll
        for (int n = 0; n < NFW; ++n) {
            const int nfg = wc * NFW + n;
            const int base = ((ks * NFB + nfg) * 64 + lane) * 8;
            bH[n] = *(const short8*)&WpH[base];
            bL[n] = *(const short8*)&WpL[base];
        }
#pragma unroll
        for (int m = 0; m < MF; ++m) {
            const int mf = wr * MF + m;
            const short8 aH = *(const short8*)&AsH[mf][lane * 8];
            const short8 aL = *(const short8*)&AsL[mf][lane * 8];
#pragma unroll
            for (int n = 0; n < NFW; ++n) {
                acc[m][n] = __builtin_amdgcn_mfma_f32_16x16x32_bf16(aH, bH[n], acc[m][n], 0, 0, 0);
                acc[m][n] = __builtin_amdgcn_mfma_f32_16x16x32_bf16(aH, bL[n], acc[m][n], 0, 0, 0);
                acc[m][n] = __builtin_amdgcn_mfma_f32_16x16x32_bf16(aL, bH[n], acc[m][n], 0, 0, 0);
            }
        }
        __syncthreads();
    }

#pragma unroll
    for (int m = 0; m < MF; ++m) {
#pragma unroll
        for (int n = 0; n < NFW; ++n) {
            const int row0 = r0 + wr * WTM + m * 16 + ((lane >> 4) << 2);
            const int cn = wc * (NFW * 16) + n * 16 + (lane & 15);
#pragma unroll
            for (int r = 0; r < 4; ++r) {
                if (row0 + r < N) Out[(size_t)(row0 + r) * BN + cn] = acc[m][n][r];
            }
        }
    }
}

// CSR gather aggregation. NPW nodes per wave, 64/NPW lanes per node,
// float2 per lane. Inner edge loop unrolled x8 for MLP.
template <int COLS, int NPW>
__global__ __launch_bounds__(256) void agg_csr(const int* __restrict__ rowptr,
                                               const int* __restrict__ col,
                                               const float* __restrict__ dis,
                                               const float* __restrict__ H,
                                               const float* __restrict__ bias,
                                               float* __restrict__ Out, int N) {
    constexpr int LPN = 64 / NPW;        // lanes per node
    static_assert(COLS == LPN * 2, "float2 per lane");
    const int gw = (int)((blockIdx.x * blockDim.x + threadIdx.x) >> 6);
    const int lane = threadIdx.x & 63;
    const int sub = lane / LPN;
    const int sl = lane % LPN;
    const int lbase = sub * LPN;
    const int node = gw * NPW + sub;

    float acc0 = 0.f, acc1 = 0.f;
    int base = 0, len = 0;
    if (node < N) {
        base = rowptr[node];
        len = rowptr[node + 1] - base;
    }

    for (int j0 = 0; j0 < len; j0 += LPN) {
        const int remain = min(LPN, len - j0);
        const int sidx = (sl < remain) ? col[base + j0 + sl] : 0;
        const float sw = (sl < remain) ? dis[sidx] : 0.f;
        int j = 0;
        for (; j + 8 <= remain; j += 8) {
            float2 hv[8];
            float w8[8];
#pragma unroll
            for (int u = 0; u < 8; ++u) {
                const int s = __shfl(sidx, lbase + j + u);
                w8[u] = __shfl(sw, lbase + j + u);
                hv[u] = *(const float2*)(H + (size_t)s * COLS + sl * 2);
            }
#pragma unroll
            for (int u = 0; u < 8; ++u) {
                acc0 = fmaf(hv[u].x, w8[u], acc0);
                acc1 = fmaf(hv[u].y, w8[u], acc1);
            }
        }
        for (; j < remain; ++j) {
            const int s = __shfl(sidx, lbase + j);
            const float w = __shfl(sw, lbase + j);
            const float2 hv = *(const float2*)(H + (size_t)s * COLS + sl * 2);
            acc0 = fmaf(hv.x, w, acc0);
            acc1 = fmaf(hv.y, w, acc1);
        }
    }

    if (node < N) {
        const float dd = dis[node];
        const float2 hs = *(const float2*)(H + (size_t)node * COLS + sl * 2);
        const float2 bv = *(const float2*)(bias + sl * 2);
        float2 o;
        o.x = fmaxf(fmaf(acc0, dd, hs.x * dd * dd) + bv.x, 0.f);
        o.y = fmaxf(fmaf(acc1, dd, hs.y * dd * dd) + bv.y, 0.f);
        *(float2*)(Out + (size_t)node * COLS + sl * 2) = o;
    }
}

// mean-pool prep: wave = 32 consecutive rows, lane = column.
// 32 unrolled independent loads -> registers, then run-length accumulate,
// ~1 atomic per lane per strip (batch is sorted).
__global__ __launch_bounds__(256) void pool_kernel(const float* __restrict__ H,
                                                   const int* __restrict__ batch,
                                                   float* __restrict__ pooled,
                                                   float* __restrict__ cnt, int N) {
    const int c = threadIdx.x & 63;
    const int w = threadIdx.x >> 6;          // wave 0..3
    const int row0 = blockIdx.x * 128 + w * 32;
    if (row0 >= N) return;
    const int nr = min(32, N - row0);

    float v[32];
    int b[32];
#pragma unroll
    for (int i = 0; i < 32; ++i) {
        const int r = row0 + i;
        if (i < nr) {
            v[i] = H[(size_t)r * 64 + c];
            b[i] = batch[r];
        } else {
            v[i] = 0.f;
            b[i] = -1;
        }
    }
    int cur = b[0];
    float sum = 0.f, csum = 0.f;
#pragma unroll
    for (int i = 0; i < 32; ++i) {
        if (i < nr) {
            if (b[i] != cur) {
                atomicAdd(&pooled[cur * 64 + c], sum);
                if (c == 0) atomicAdd(&cnt[cur], csum);
                cur = b[i];
                sum = 0.f;
                csum = 0.f;
            }
            sum += v[i];
            csum += 1.f;
        }
    }
    atomicAdd(&pooled[cur * 64 + c], sum);
    if (c == 0) atomicAdd(&cnt[cur], csum);
}

__global__ __launch_bounds__(256) void final_kernel(const float* __restrict__ pooled,
                                                    const float* __restrict__ cnt,
                                                    const float* __restrict__ Wlin,
                                                    const float* __restrict__ blin,
                                                    float* __restrict__ out) {
    const int t = threadIdx.x;
    const int g = t >> 1, o = t & 1;
    const float inv = 1.0f / fmaxf(cnt[g], 1.0f);
    float s = 0.f;
#pragma unroll
    for (int j = 0; j < 64; ++j) s = fmaf(pooled[g * 64 + j], Wlin[j * 2 + o], s);
    out[t] = s * inv + blin[o];
}

extern "C" void kernel_launch(void* const* d_in, const int* in_sizes, int n_in,
                              void* d_out, int out_size, void* d_ws, size_t ws_size,
                              hipStream_t stream) {
    const float* x     = (const float*)d_in[0];
    const int*   edge  = (const int*)d_in[1];
    const int*   batch = (const int*)d_in[2];
    const float* W1    = (const float*)d_in[3];
    const float* b1    = (const float*)d_in[4];
    const float* W2    = (const float*)d_in[5];
    const float* b2    = (const float*)d_in[6];
    const float* Wlin  = (const float*)d_in[7];
    const float* blin  = (const float*)d_in[8];
    float* out = (float*)d_out;

    const int N = NN;
    const int E = in_sizes[1] / 2;
    const int* src = edge;
    const int* dst = edge + E;
    const int NB = (N + SCHUNK - 1) / SCHUNK;  // 98

    char* ws = (char*)d_ws;
    size_t off = 0;
    auto alloc = [&](size_t bytes) -> void* {
        void* p = ws + off;
        off += (bytes + 511) & ~(size_t)511;
        return p;
    };
    int*   deg    = (int*)alloc((size_t)N * 4);
    float* dis    = (float*)alloc((size_t)N * 4);
    int*   rowptr = (int*)alloc((size_t)(N + 1) * 4);
    int*   fill   = (int*)alloc((size_t)N * 4);
    int*   bsum   = (int*)alloc((size_t)NB * 4);
    int*   col    = (int*)alloc((size_t)E * 4);
    unsigned short* w1h = (unsigned short*)alloc((size_t)384 * 128 * 2);
    unsigned short* w1l = (unsigned short*)alloc((size_t)384 * 128 * 2);
    unsigned short* w2h = (unsigned short*)alloc((size_t)128 * 64 * 2);
    unsigned short* w2l = (unsigned short*)alloc((size_t)128 * 64 * 2);
    float* h1     = (float*)alloc((size_t)N * 128 * 4);
    float* agg1   = (float*)alloc((size_t)N * 128 * 4);
    float* pooled = (float*)alloc((size_t)NG * 64 * 4);
    float* cnt    = (float*)alloc((size_t)NG * 4);
    float* h2   = h1;
    float* agg2 = (float*)((char*)h1 + (size_t)N * 64 * 4);

    hipMemsetAsync(deg, 0, (size_t)N * 4, stream);
    hipMemsetAsync(fill, 0, (size_t)N * 4, stream);
    hipMemsetAsync(pooled, 0, (size_t)NG * 64 * 4, stream);
    hipMemsetAsync(cnt, 0, (size_t)NG * 4, stream);

    // weight packing (tiny, once per call)
    pack_w<<<(384 * 128 + 255) / 256, 256, 0, stream>>>(W1, w1h, w1l, 384, 128);
    pack_w<<<(128 * 64 + 255) / 256, 256, 0, stream>>>(W2, w2h, w2l, 128, 64);

    // degree + CSR build + normalization
    deg_kernel<<<2048, 256, 0, stream>>>(dst, deg, E);
    scan_part<<<NB, 256, 0, stream>>>(deg, bsum, N);
    scan_top<<<1, 128, 0, stream>>>(bsum, NB);
    scan_write<<<NB, 256, 0, stream>>>(deg, bsum, rowptr, dis, N, NB);
    csr_fill<<<2048, 256, 0, stream>>>(src, dst, rowptr, fill, col, E);

    const int gblocks = (N + 127) / 128;
    // layer 1
    gemm_mfma<128><<<gblocks, 256, 0, stream>>>(x, w1h, w1l, h1, N, 384);
    agg_csr<128, 1><<<(N + 3) / 4, 256, 0, stream>>>(rowptr, col, dis, h1, b1, agg1, N);

    // layer 2
    gemm_mfma<64><<<gblocks, 256, 0, stream>>>(agg1, w2h, w2l, h2, N, 128);
    agg_csr<64, 2><<<(N + 7) / 8, 256, 0, stream>>>(rowptr, col, dis, h2, b2, agg2, N);

    // pool + head
    pool_kernel<<<(N + 127) / 128, 256, 0, stream>>>(agg2, batch, pooled, cnt, N);
    final_kernel<<<1, 256, 0, stream>>>(pooled, cnt, Wlin, blin, out);
}